// Round 1
// baseline (1502.104 us; speedup 1.0000x reference)
//
#include <hip/hip_runtime.h>
#include <math.h>

// ---------------------------------------------------------------------------
// WinFuncSelfAttention: full Fourier-domain pipeline.
//   B=16 windows, S=16 tokens, C=128 ch, H=8 heads, D=16, P=32, modes 16x16.
//   X    = low-mode rfft2 of shifted input, layout [bs][mode][c] float2
//   QKVm = per-mode complex GEMM X * Wqkv' (384 out)   [bs][mode][o]
//   scores = spatialGram(x) + Parseval cross/mix terms (ky=0 c2r projection
//            handled exactly: weight-1 cross at ky=0; QK term ReQ*ReK at DC,
//            1/2 at kx>=1,ky=0)
//   attn = softmax(scores/4096 + mask + logCPB)
//   SAf  = attn @ (X + Vm~) at low modes (Vm~: ky=0 projection)
//   OUTm = per-mode GEMM SAf * Wout'
//   out  = unshift(irfft2(pad(OUTm)))  (c2r: only Re of ky=0 column used)
// ---------------------------------------------------------------------------

#define DEVI __device__ __forceinline__

// ---------------- K0: bias = attn_mask + log-CPB MLP -----------------------
__global__ __launch_bounds__(256) void k_bias(
    const float* __restrict__ w1, const float* __restrict__ b1,
    const float* __restrict__ w2, const float* __restrict__ amask,
    float* __restrict__ biasb) {
  __shared__ float w1s[1024];
  __shared__ float b1s[512];
  __shared__ float w2s[4096];
  int t = threadIdx.x;
  for (int k = t; k < 1024; k += 256) w1s[k] = w1[k];
  for (int k = t; k < 512; k += 256) b1s[k] = b1[k];
  for (int k = t; k < 4096; k += 256) w2s[k] = w2[k];
  __syncthreads();
  int i = t >> 4, j = t & 15;
  float r0 = (float)((i >> 2) - (j >> 2));
  float r1 = (float)((i & 3) - (j & 3));
  const float sc = 8.0f / 3.0f;  // 8 / log2(8)
  float f0 = (r0 == 0.f) ? 0.f : copysignf(log2f(1.f + fabsf(r0)) * sc, r0);
  float f1 = (r1 == 0.f) ? 0.f : copysignf(log2f(1.f + fabsf(r1)) * sc, r1);
  float o[8];
#pragma unroll
  for (int h = 0; h < 8; h++) o[h] = 0.f;
  for (int k = 0; k < 512; k++) {
    float hd = f0 * w1s[k] + f1 * w1s[512 + k] + b1s[k];
    hd = fmaxf(hd, 0.f);
#pragma unroll
    for (int h = 0; h < 8; h++) o[h] += hd * w2s[k * 8 + h];
  }
  for (int w = 0; w < 4; w++)
#pragma unroll
    for (int h = 0; h < 8; h++) {
      int idx = ((w * 8 + h) * 16 + i) * 16 + j;
      biasb[idx] = amask[idx] + o[h];
    }
}

// ---------------- T: weight transpose wr/wi[c][o][m] -> dst[m][c][o] -------
__global__ __launch_bounds__(256) void k_transpose_w(
    const float* __restrict__ wr, const float* __restrict__ wi,
    float2* __restrict__ dst, int N) {
  __shared__ float2 ld[256][17];
  int t = threadIdx.x;
  int ob = blockIdx.x * 16;
  int cb = blockIdx.y * 8;
  for (int cc = 0; cc < 8; cc++) {
    int c = cb + cc;
    for (int oo = 0; oo < 16; oo++) {
      size_t si = ((size_t)c * N + ob + oo) * 256 + t;
      ld[t][oo] = make_float2(wr[si], wi[si]);
    }
    __syncthreads();
    {
      int oo = t & 15, tq = t >> 4;
#pragma unroll
      for (int mr = 0; mr < 16; mr++) {
        int m = mr * 16 + tq;
        dst[((size_t)m * 128 + c) * N + ob + oo] = ld[m][oo];
      }
    }
    __syncthreads();
  }
}

// ---------------- K1: shift-gather + forward low-mode DFT ------------------
__global__ __launch_bounds__(256) void k_fwd_dft(
    const float* __restrict__ seq, float2* __restrict__ Xlow) {
  __shared__ float tile[32][33];
  __shared__ float2 t1[32][17];
  __shared__ float2 outbuf[256][8];
  __shared__ float2 tw[32];
  int t = threadIdx.x;
  int cbase = blockIdx.x * 32;
  int bs = blockIdx.y;
  int b = bs >> 4, s = bs & 15;
  int qx = s >> 2, qy = s & 3;
  if (t < 32) {
    float sv, cv;
    sincosf(6.283185307179586f * (float)t / 32.f, &sv, &cv);
    tw[t] = make_float2(cv, sv);
  }
  __syncthreads();
  for (int cc = 0; cc < 32; cc++) {
    int c = cbase + cc;
#pragma unroll
    for (int k = 0; k < 4; k++) {
      int px = t + k * 256;
      int u = px >> 5, v = px & 31;
      int uu = u + 16, vv = v + 16;
      int u2 = uu & 31, v2 = vv & 31;
      int qx2 = (qx + (uu >> 5)) & 3, qy2 = (qy + (vv >> 5)) & 3;
      tile[u][v] = seq[(((size_t)(b * 16 + qx2 * 4 + qy2) * 128 + c) << 10) +
                       (u2 << 5) + v2];
    }
    __syncthreads();
    {  // stage1: t1[u][ky] = sum_v tile[u][v] e^{-2pi i ky v/32}
      int u = t >> 3, kp = t & 7;
#pragma unroll
      for (int q = 0; q < 2; q++) {
        int ky = kp * 2 + q;
        float tr = 0.f, ti = 0.f;
#pragma unroll
        for (int v = 0; v < 32; v++) {
          float x = tile[u][v];
          float2 w = tw[(ky * v) & 31];
          tr += x * w.x;
          ti -= x * w.y;
        }
        t1[u][ky] = make_float2(tr, ti);
      }
    }
    __syncthreads();
    {  // stage2: X[kx][ky] = sum_u t1[u][ky] e^{-2pi i kx u/32}
      int kx = t >> 4, ky = t & 15;
      float xr = 0.f, xi = 0.f;
#pragma unroll
      for (int u = 0; u < 32; u++) {
        float2 g = t1[u][ky];
        float2 w = tw[(kx * u) & 31];
        xr += g.x * w.x + g.y * w.y;
        xi += g.y * w.x - g.x * w.y;
      }
      outbuf[t][cc & 7] = make_float2(xr, xi);
    }
    __syncthreads();
    if ((cc & 7) == 7) {
      int cl = t & 7, mq = t >> 3;
      int cfb = c - 7;
#pragma unroll
      for (int pass = 0; pass < 8; pass++) {
        int m = pass * 32 + mq;
        Xlow[((size_t)bs * 256 + m) * 128 + cfb + cl] = outbuf[m][cl];
      }
      __syncthreads();
    }
  }
}

// ---------------- K1G: spatial Gram of shifted x (scores XX term) ----------
__global__ __launch_bounds__(256) void k_gram(
    const float* __restrict__ seq, float* __restrict__ Gpart) {
  __shared__ float xt[16][65];
  int t = threadIdx.x;
  int dc = blockIdx.x;
  int bh = blockIdx.y;
  int b = bh >> 3, h = bh & 7;
  int i = t >> 4, j = t & 15;
  float acc = 0.f;
  for (int dd = 0; dd < 4; dd++) {
    int c = h * 16 + dc * 4 + dd;
    for (int ch = 0; ch < 16; ch++) {
      {
        int s = t >> 4, pbase = (t & 15) * 4;
        int qx = s >> 2, qy = s & 3;
#pragma unroll
        for (int k = 0; k < 4; k++) {
          int px = ch * 64 + pbase + k;
          int u = px >> 5, v = px & 31;
          int uu = u + 16, vv = v + 16;
          int u2 = uu & 31, v2 = vv & 31;
          int qx2 = (qx + (uu >> 5)) & 3, qy2 = (qy + (vv >> 5)) & 3;
          xt[s][pbase + k] =
              seq[(((size_t)(b * 16 + qx2 * 4 + qy2) * 128 + c) << 10) +
                  (u2 << 5) + v2];
        }
      }
      __syncthreads();
#pragma unroll 16
      for (int p = 0; p < 64; p++) acc += xt[i][p] * xt[j][p];
      __syncthreads();
    }
  }
  Gpart[((size_t)(dc * 16 + b) * 8 + h) * 256 + t] = acc;
}

// ---------------- K2/K5: per-mode complex GEMM [256bs x 128] @ [128 x N] ---
__global__ __launch_bounds__(256) void k_mix(
    const float2* __restrict__ A, const float2* __restrict__ W,
    float2* __restrict__ C, int N) {
  __shared__ float2 At[64][17];
  __shared__ float2 Bt[16][65];
  int t = threadIdx.x;
  int ot = blockIdx.x, bt = blockIdx.y, m = blockIdx.z;
  int tx = t & 15, ty = t >> 4;
  float accr[4][4], acci[4][4];
#pragma unroll
  for (int r = 0; r < 4; r++)
#pragma unroll
    for (int o = 0; o < 4; o++) {
      accr[r][o] = 0.f;
      acci[r][o] = 0.f;
    }
  for (int ks = 0; ks < 8; ks++) {
    int k0 = ks * 16;
    {
      int r = t >> 2, kb = (t & 3) * 4;
      const float2* src = &A[((size_t)(bt * 64 + r) * 256 + m) * 128 + k0 + kb];
#pragma unroll
      for (int k = 0; k < 4; k++) At[r][kb + k] = src[k];
    }
    {
      int kc = t >> 4, ob = (t & 15) * 4;
      const float2* src = &W[((size_t)m * 128 + k0 + kc) * N + ot * 64 + ob];
#pragma unroll
      for (int k = 0; k < 4; k++) Bt[kc][ob + k] = src[k];
    }
    __syncthreads();
#pragma unroll
    for (int kc = 0; kc < 16; kc++) {
      float2 a[4], bv[4];
#pragma unroll
      for (int r = 0; r < 4; r++) a[r] = At[ty + r * 16][kc];
#pragma unroll
      for (int o = 0; o < 4; o++) bv[o] = Bt[kc][tx + o * 16];
#pragma unroll
      for (int r = 0; r < 4; r++)
#pragma unroll
        for (int o = 0; o < 4; o++) {
          accr[r][o] += a[r].x * bv[o].x - a[r].y * bv[o].y;
          acci[r][o] += a[r].x * bv[o].y + a[r].y * bv[o].x;
        }
    }
    __syncthreads();
  }
#pragma unroll
  for (int r = 0; r < 4; r++) {
    size_t row = (size_t)(bt * 64 + ty + r * 16) * 256 + m;
#pragma unroll
    for (int o = 0; o < 4; o++)
      C[row * N + ot * 64 + tx + o * 16] = make_float2(accr[r][o], acci[r][o]);
  }
}

// ---------------- K3: score partials over low modes ------------------------
__global__ __launch_bounds__(256) void k_scores(
    const float2* __restrict__ Xlow, const float2* __restrict__ QKVm,
    float* __restrict__ Spart) {
  __shared__ float2 Xs[16][17], Qs[16][17], Ks[16][17];
  int t = threadIdx.x;
  int mc = blockIdx.x;
  int bh = blockIdx.y;
  int b = bh >> 3, h = bh & 7;
  int i = t >> 4, j = t & 15;
  int s = i, d = j;  // loader role
  size_t base = (size_t)(b * 16 + s) * 256;
  int m0 = mc * 32;
  float2 px = Xlow[(base + m0) * 128 + h * 16 + d];
  float2 pq = QKVm[(base + m0) * 384 + h * 16 + d];
  float2 pk = QKVm[(base + m0) * 384 + 128 + h * 16 + d];
  float acc = 0.f;
  for (int mm = 0; mm < 32; mm++) {
    int m = m0 + mm;
    Xs[s][d] = px;
    Qs[s][d] = pq;
    Ks[s][d] = pk;
    __syncthreads();
    if (mm < 31) {
      px = Xlow[(base + m + 1) * 128 + h * 16 + d];
      pq = QKVm[(base + m + 1) * 384 + h * 16 + d];
      pk = QKVm[(base + m + 1) * 384 + 128 + h * 16 + d];
    }
    int ky = m & 15, kx = m >> 4;
    if (ky > 0) {
#pragma unroll
      for (int dd = 0; dd < 16; dd++) {
        float2 Xi = Xs[i][dd], Qi = Qs[i][dd], Xj = Xs[j][dd], Kj = Ks[j][dd];
        float qr = Xi.x + Qi.x, qi = Xi.y + Qi.y;
        float kr = Xj.x + Kj.x, ki = Xj.y + Kj.y;
        acc += 2.f * (qr * kr + qi * ki - (Xi.x * Xj.x + Xi.y * Xj.y));
      }
    } else {
#pragma unroll
      for (int dd = 0; dd < 16; dd++) {
        float2 Xi = Xs[i][dd], Qi = Qs[i][dd], Xj = Xs[j][dd], Kj = Ks[j][dd];
        float cr = Xi.x * Kj.x + Xi.y * Kj.y + Qi.x * Xj.x + Qi.y * Xj.y;
        float qk = (kx == 0) ? (Qi.x * Kj.x)
                             : 0.5f * (Qi.x * Kj.x + Qi.y * Kj.y);
        acc += cr + qk;
      }
    }
    __syncthreads();
  }
  Spart[((size_t)mc * 128 + bh) * 256 + t] = acc;
}

// ---------------- K3b: assemble scores, bias, softmax ----------------------
__global__ __launch_bounds__(256) void k_softmax(
    const float* __restrict__ Spart, const float* __restrict__ Gpart,
    const float* __restrict__ biasb, float* __restrict__ attn) {
  int t = threadIdx.x;
  int bh = blockIdx.x;
  int b = bh >> 3, h = bh & 7;
  int i = t >> 4, j = t & 15;
  float acc = 0.f;
#pragma unroll
  for (int mc = 0; mc < 8; mc++) acc += Spart[((size_t)mc * 128 + bh) * 256 + t];
  float G = 0.f;
#pragma unroll
  for (int dc = 0; dc < 4; dc++) G += Gpart[((size_t)(dc * 16 + b) * 8 + h) * 256 + t];
  float score = G * (1.f / 4096.f) + acc * (1.f / 4194304.f) +
                biasb[(((b & 3) * 8 + h) * 16 + i) * 16 + j];
  float mx = score;
#pragma unroll
  for (int o = 8; o >= 1; o >>= 1) mx = fmaxf(mx, __shfl_xor(mx, o, 16));
  float e = expf(score - mx);
  float sm = e;
#pragma unroll
  for (int o = 8; o >= 1; o >>= 1) sm += __shfl_xor(sm, o, 16);
  attn[(size_t)bh * 256 + t] = e / sm;
}

// ---------------- K4: SAf[bs][m][c] = attn @ (X + Vm~) ---------------------
__global__ __launch_bounds__(256) void k_sav(
    const float2* __restrict__ Xlow, const float2* __restrict__ QKVm,
    const float* __restrict__ attn, float2* __restrict__ SAf) {
  __shared__ float at[8][16][17];
  __shared__ float2 vt[16][130];
  int t = threadIdx.x;
  int mc = blockIdx.x;
  int b = blockIdx.y;
  {
    int h = t >> 5, ii = (t >> 1) & 15, jb = (t & 1) * 8;
#pragma unroll
    for (int k = 0; k < 8; k++)
      at[h][ii][jb + k] = attn[((size_t)(b * 8 + h) * 16 + ii) * 16 + jb + k];
  }
  __syncthreads();
  int i = t >> 4, cg = t & 15;
  for (int mm = 0; mm < 16; mm++) {
    int m = mc * 16 + mm;
    int ky = m & 15, kx = m >> 4;
    {
      int jj = t >> 4;
      size_t row = (size_t)(b * 16 + jj) * 256 + m;
#pragma unroll
      for (int u = 0; u < 8; u++) {
        int c = cg + u * 16;
        float2 vm = QKVm[row * 384 + 256 + c];
        float2 xv = Xlow[row * 128 + c];
        float2 vh;
        if (ky == 0) {
          if (kx == 0)
            vh = make_float2(xv.x + vm.x, xv.y);  // drop Im(Vm) at DC
          else
            vh = make_float2(xv.x + 0.5f * vm.x, xv.y + 0.5f * vm.y);
        } else
          vh = make_float2(xv.x + vm.x, xv.y + vm.y);
        vt[jj][c] = vh;
      }
    }
    __syncthreads();
    float2 o8[8];
#pragma unroll
    for (int u = 0; u < 8; u++) o8[u] = make_float2(0.f, 0.f);
#pragma unroll
    for (int jj = 0; jj < 16; jj++) {
#pragma unroll
      for (int u = 0; u < 8; u++) {
        float av = at[u][i][jj];
        float2 v = vt[jj][cg + u * 16];
        o8[u].x += av * v.x;
        o8[u].y += av * v.y;
      }
    }
    size_t orow = (size_t)(b * 16 + i) * 256 + m;
#pragma unroll
    for (int u = 0; u < 8; u++) SAf[orow * 128 + cg + u * 16] = o8[u];
    __syncthreads();
  }
}

// ---------------- K6: inverse DFT (c2r semantics) + un-shift scatter -------
__global__ __launch_bounds__(256) void k_irfft_out(
    const float2* __restrict__ OUTm, float* __restrict__ out) {
  __shared__ float2 Fm[256][17];
  __shared__ float2 gb[17][33];
  __shared__ float2 tw[32];
  int t = threadIdx.x;
  int oc = blockIdx.x;
  int bs = blockIdx.y;
  int b = bs >> 4, s = bs & 15;
  int qx = s >> 2, qy = s & 3;
  if (t < 32) {
    float sv, cv;
    sincosf(6.283185307179586f * (float)t / 32.f, &sv, &cv);
    tw[t] = make_float2(cv, sv);
  }
  {
    const float2* src = &OUTm[((size_t)bs * 256 + t) * 128 + oc * 16];
#pragma unroll
    for (int oo = 0; oo < 16; oo++) Fm[t][oo] = src[oo];
  }
  __syncthreads();
  for (int oo = 0; oo < 16; oo++) {
    {  // stage1: g[x][ky] = sum_kx F e^{+2pi i kx x/32}   (unscaled)
      int x = t >> 3, kp = t & 7;
#pragma unroll
      for (int q = 0; q < 2; q++) {
        int ky = kp * 2 + q;
        float gr = 0.f, gi = 0.f;
#pragma unroll
        for (int kx = 0; kx < 16; kx++) {
          float2 F = Fm[kx * 16 + ky][oo];
          float2 w = tw[(kx * x) & 31];
          gr += F.x * w.x - F.y * w.y;
          gi += F.x * w.y + F.y * w.x;
        }
        gb[ky][x] = make_float2(gr, gi);
      }
    }
    __syncthreads();
    {  // stage2: out[x][y] = (gr0 + 2 sum_{ky=1..15} Re(g e^{+i th}))/1024
      int x = t >> 3, yb = (t & 7) * 4;
      float vals[4];
#pragma unroll
      for (int k = 0; k < 4; k++) {
        int y = yb + k;
        float v = gb[0][x].x;
#pragma unroll
        for (int ky = 1; ky < 16; ky++) {
          float2 g = gb[ky][x];
          float2 w = tw[(ky * y) & 31];
          v += 2.f * (g.x * w.x - g.y * w.y);
        }
        vals[k] = v * (1.f / 1024.f);
      }
      int uu = x + 16;
      int u2 = uu & 31;
      int qx2 = (qx + (uu >> 5)) & 3;
      int vv = yb + 16;
      int v2 = vv & 31;
      int qy2 = (qy + (vv >> 5)) & 3;
      int s2 = qx2 * 4 + qy2;
      int o_abs = oc * 16 + oo;
      float* dst = &out[(((size_t)(b * 16 + s2) * 128 + o_abs) << 10) +
                        (u2 << 5) + v2];
      *(float4*)dst = make_float4(vals[0], vals[1], vals[2], vals[3]);
    }
    __syncthreads();
  }
}

// ---------------------------------------------------------------------------
extern "C" void kernel_launch(void* const* d_in, const int* in_sizes, int n_in,
                              void* d_out, int out_size, void* d_ws,
                              size_t ws_size, hipStream_t stream) {
  (void)in_sizes;
  (void)n_in;
  const float* seq = (const float*)d_in[0];
  const float* qwr = (const float*)d_in[1];
  const float* qwi = (const float*)d_in[2];
  const float* owr = (const float*)d_in[3];
  const float* owi = (const float*)d_in[4];
  const float* cw1 = (const float*)d_in[5];
  const float* cb1 = (const float*)d_in[6];
  const float* cw2 = (const float*)d_in[7];
  const float* amask = (const float*)d_in[8];
  float* out = (float*)d_out;
  char* ws = (char*)d_ws;

  size_t off = 0;
  float2* Xlow = (float2*)(ws + off);           // 67,108,864
  float2* OUTm = Xlow;                          // alias (live after K4)
  off += (size_t)256 * 256 * 128 * 8;
  float2* QKVm = (float2*)(ws + off);           // 201,326,592
  off += (size_t)256 * 256 * 384 * 8;
  float2* Wq = (float2*)(ws + off);             // 100,663,296
  float2* SAf = Wq;                             // alias (live after K2)
  off += (size_t)256 * 128 * 384 * 8;
  float2* Wo = (float2*)(ws + off);             // 33,554,432
  off += (size_t)256 * 128 * 128 * 8;
  float* Gpart = (float*)(ws + off);            // 524,288
  off += (size_t)4 * 16 * 8 * 256 * 4;
  float* biasb = (float*)(ws + off);            // 32,768
  off += (size_t)4 * 8 * 256 * 4;
  float* attn = (float*)(ws + off);             // 131,072
  off += (size_t)16 * 8 * 256 * 4;
  float* Spart = (float*)(ws + off);            // 1,048,576
  off += (size_t)8 * 128 * 256 * 4;

  if (ws_size < off) {  // insufficient scratch: fail loudly but safely
    hipMemsetAsync(d_out, 0, (size_t)out_size * 4, stream);
    return;
  }

  dim3 blk(256);
  k_transpose_w<<<dim3(24, 16), blk, 0, stream>>>(qwr, qwi, Wq, 384);
  k_transpose_w<<<dim3(8, 16), blk, 0, stream>>>(owr, owi, Wo, 128);
  k_bias<<<dim3(1), blk, 0, stream>>>(cw1, cb1, cw2, amask, biasb);
  k_fwd_dft<<<dim3(4, 256), blk, 0, stream>>>(seq, Xlow);
  k_gram<<<dim3(4, 128), blk, 0, stream>>>(seq, Gpart);
  k_mix<<<dim3(6, 4, 256), blk, 0, stream>>>(Xlow, Wq, QKVm, 384);
  k_scores<<<dim3(8, 128), blk, 0, stream>>>(Xlow, QKVm, Spart);
  k_softmax<<<dim3(128), blk, 0, stream>>>(Spart, Gpart, biasb, attn);
  k_sav<<<dim3(16, 16), blk, 0, stream>>>(Xlow, QKVm, attn, SAf);
  k_mix<<<dim3(2, 4, 256), blk, 0, stream>>>(SAf, Wo, OUTm, 128);
  k_irfft_out<<<dim3(8, 256), blk, 0, stream>>>(OUTm, out);
}

// Round 2
// 1013.548 us; speedup vs baseline: 1.4820x; 1.4820x over previous
//
#include <hip/hip_runtime.h>
#include <hip/hip_bf16.h>
#include <math.h>

// ---------------------------------------------------------------------------
// WinFuncSelfAttention, Fourier-domain, mode-major layouts:
//   Xlow  fp32  float2 [m][bs][128]     (low-mode DFT of shifted input)
//   Xbf   bf16  [m][bs][256]            (same, interleaved re/im, MFMA A)
//   Wqb   bf16  [m][768][256]           (B' = [[Br,Bi],[-Bi,Br]], N-major)
//   QKVmb bf16  ushort2 [m][bs][384]    (Qm,Km,Vm)
//   SAfb  bf16  ushort2 [m][bs][128]
//   OUTm  fp32  float2 [m][bs][128]
// mix GEMMs run on v_mfma_f32_16x16x32_bf16 (128x128 tile, 4 waves, BK=64,
// XOR-swizzled LDS).
// ---------------------------------------------------------------------------

#define DEVI __device__ __forceinline__
typedef unsigned short u16;
typedef unsigned int u32;
typedef __attribute__((ext_vector_type(8))) short short8;
typedef __attribute__((ext_vector_type(4))) float f32x4;

DEVI u16 f2b(float f) {
  union { __hip_bfloat16 h; u16 u; } cv;
  cv.h = __float2bfloat16(f);
  return cv.u;
}
DEVI float b2f(u16 u) { return __uint_as_float(((u32)u) << 16); }

// ---------------- K0: bias = attn_mask + log-CPB MLP -----------------------
__global__ __launch_bounds__(256) void k_bias(
    const float* __restrict__ w1, const float* __restrict__ b1,
    const float* __restrict__ w2, const float* __restrict__ amask,
    float* __restrict__ biasb) {
  __shared__ float w1s[1024];
  __shared__ float b1s[512];
  __shared__ float w2s[4096];
  int t = threadIdx.x;
  for (int k = t; k < 1024; k += 256) w1s[k] = w1[k];
  for (int k = t; k < 512; k += 256) b1s[k] = b1[k];
  for (int k = t; k < 4096; k += 256) w2s[k] = w2[k];
  __syncthreads();
  int i = t >> 4, j = t & 15;
  float r0 = (float)((i >> 2) - (j >> 2));
  float r1 = (float)((i & 3) - (j & 3));
  const float sc = 8.0f / 3.0f;  // 8 / log2(8)
  float f0 = (r0 == 0.f) ? 0.f : copysignf(log2f(1.f + fabsf(r0)) * sc, r0);
  float f1 = (r1 == 0.f) ? 0.f : copysignf(log2f(1.f + fabsf(r1)) * sc, r1);
  float o[8];
#pragma unroll
  for (int h = 0; h < 8; h++) o[h] = 0.f;
  for (int k = 0; k < 512; k++) {
    float hd = f0 * w1s[k] + f1 * w1s[512 + k] + b1s[k];
    hd = fmaxf(hd, 0.f);
#pragma unroll
    for (int h = 0; h < 8; h++) o[h] += hd * w2s[k * 8 + h];
  }
  for (int w = 0; w < 4; w++)
#pragma unroll
    for (int h = 0; h < 8; h++) {
      int idx = ((w * 8 + h) * 16 + i) * 16 + j;
      biasb[idx] = amask[idx] + o[h];
    }
}

// ---------------- T: weight transpose wr/wi[c][o][m] -> dst[m][c][o] -------
__global__ __launch_bounds__(256) void k_transpose_w(
    const float* __restrict__ wr, const float* __restrict__ wi,
    float2* __restrict__ dst, int N) {
  __shared__ float2 ld[256][17];
  int t = threadIdx.x;
  int ob = blockIdx.x * 16;
  int cb = blockIdx.y * 8;
  for (int cc = 0; cc < 8; cc++) {
    int c = cb + cc;
    for (int oo = 0; oo < 16; oo++) {
      size_t si = ((size_t)c * N + ob + oo) * 256 + t;
      ld[t][oo] = make_float2(wr[si], wi[si]);
    }
    __syncthreads();
    {
      int oo = t & 15, tq = t >> 4;
#pragma unroll
      for (int mr = 0; mr < 16; mr++) {
        int m = mr * 16 + tq;
        dst[((size_t)m * 128 + c) * N + ob + oo] = ld[m][oo];
      }
    }
    __syncthreads();
  }
}

// ---------------- B-build: Ws1[m][c][o] f32 -> Bt[m][n=2o+p][k=2c+q] bf16 --
template <int N>
__global__ __launch_bounds__(256) void k_build_b(
    const float2* __restrict__ Ws1, u16* __restrict__ Bt) {
  __shared__ float2 tile[128][65];
  int t = threadIdx.x;
  int ob = blockIdx.x;  // 64-o chunk
  int m = blockIdx.y;
  {
    int c4 = t >> 6, o = t & 63;
    for (int cc = 0; cc < 32; cc++) {
      int c = cc * 4 + c4;
      tile[c][o] = Ws1[((size_t)m * 128 + c) * N + ob * 64 + o];
    }
  }
  __syncthreads();
  int l = t & 63, w2 = t >> 6;
  for (int rr = 0; rr < 32; rr++) {
    int r = w2 * 32 + rr;      // local n row
    int ol = r >> 1, p = r & 1;
    size_t rowoff = ((size_t)m * (2 * N) + (size_t)ob * 128 + r) * 256;
#pragma unroll
    for (int ch = 0; ch < 2; ch++) {
      int c = ch * 64 + l;
      float2 wv = tile[c][ol];
      float v0 = p ? wv.y : wv.x;
      float v1 = p ? wv.x : -wv.y;
      ushort2 u;
      u.x = f2b(v0);
      u.y = f2b(v1);
      *(ushort2*)(Bt + rowoff + 2 * c) = u;
    }
  }
}

// ---------------- K1: shift-gather + forward low-mode DFT ------------------
__global__ __launch_bounds__(256) void k_fwd_dft(
    const float* __restrict__ seq, float2* __restrict__ Xlow,
    ushort2* __restrict__ Xbf2) {
  __shared__ float tile[32][33];
  __shared__ float2 t1[32][17];
  __shared__ float2 outbuf[256][8];
  __shared__ float2 tw[32];
  int t = threadIdx.x;
  int cbase = blockIdx.x * 32;
  int bs = blockIdx.y;
  int b = bs >> 4, s = bs & 15;
  int qx = s >> 2, qy = s & 3;
  if (t < 32) {
    float sv, cv;
    sincosf(6.283185307179586f * (float)t / 32.f, &sv, &cv);
    tw[t] = make_float2(cv, sv);
  }
  __syncthreads();
  for (int cc = 0; cc < 32; cc++) {
    int c = cbase + cc;
#pragma unroll
    for (int k = 0; k < 4; k++) {
      int px = t + k * 256;
      int u = px >> 5, v = px & 31;
      int uu = u + 16, vv = v + 16;
      int u2 = uu & 31, v2 = vv & 31;
      int qx2 = (qx + (uu >> 5)) & 3, qy2 = (qy + (vv >> 5)) & 3;
      tile[u][v] = seq[(((size_t)(b * 16 + qx2 * 4 + qy2) * 128 + c) << 10) +
                       (u2 << 5) + v2];
    }
    __syncthreads();
    {  // stage1
      int u = t >> 3, kp = t & 7;
#pragma unroll
      for (int q = 0; q < 2; q++) {
        int ky = kp * 2 + q;
        float tr = 0.f, ti = 0.f;
#pragma unroll
        for (int v = 0; v < 32; v++) {
          float x = tile[u][v];
          float2 w = tw[(ky * v) & 31];
          tr += x * w.x;
          ti -= x * w.y;
        }
        t1[u][ky] = make_float2(tr, ti);
      }
    }
    __syncthreads();
    {  // stage2
      int kx = t >> 4, ky = t & 15;
      float xr = 0.f, xi = 0.f;
#pragma unroll
      for (int u = 0; u < 32; u++) {
        float2 g = t1[u][ky];
        float2 w = tw[(kx * u) & 31];
        xr += g.x * w.x + g.y * w.y;
        xi += g.y * w.x - g.x * w.y;
      }
      outbuf[t][cc & 7] = make_float2(xr, xi);
    }
    __syncthreads();
    if ((cc & 7) == 7) {
      int cl = t & 7, mq = t >> 3;
      int cfb = c - 7;
#pragma unroll
      for (int pass = 0; pass < 8; pass++) {
        int mI = pass * 32 + mq;
        float2 v = outbuf[mI][cl];
        size_t idx = ((size_t)mI * 256 + bs) * 128 + cfb + cl;
        Xlow[idx] = v;
        ushort2 ub;
        ub.x = f2b(v.x);
        ub.y = f2b(v.y);
        Xbf2[idx] = ub;
      }
      __syncthreads();
    }
  }
}

// ---------------- K1G: spatial Gram of shifted x ---------------------------
__global__ __launch_bounds__(256) void k_gram(
    const float* __restrict__ seq, float* __restrict__ Gpart) {
  __shared__ float xt[16][65];
  int t = threadIdx.x;
  int dc = blockIdx.x;
  int bh = blockIdx.y;
  int b = bh >> 3, h = bh & 7;
  int i = t >> 4, j = t & 15;
  float acc = 0.f;
  for (int dd = 0; dd < 4; dd++) {
    int c = h * 16 + dc * 4 + dd;
    for (int ch = 0; ch < 16; ch++) {
      {
        int s = t >> 4, pbase = (t & 15) * 4;
        int qx = s >> 2, qy = s & 3;
#pragma unroll
        for (int k = 0; k < 4; k++) {
          int px = ch * 64 + pbase + k;
          int u = px >> 5, v = px & 31;
          int uu = u + 16, vv = v + 16;
          int u2 = uu & 31, v2 = vv & 31;
          int qx2 = (qx + (uu >> 5)) & 3, qy2 = (qy + (vv >> 5)) & 3;
          xt[s][pbase + k] =
              seq[(((size_t)(b * 16 + qx2 * 4 + qy2) * 128 + c) << 10) +
                  (u2 << 5) + v2];
        }
      }
      __syncthreads();
#pragma unroll 16
      for (int p = 0; p < 64; p++) acc += xt[i][p] * xt[j][p];
      __syncthreads();
    }
  }
  Gpart[((size_t)(dc * 16 + b) * 8 + h) * 256 + t] = acc;
}

// ---------------- MFMA per-mode GEMM: C[m] = A[m] (256x256) @ B[m]^T' ------
// A bf16 [m][256][256]; B bf16 [m][NP][256] (N-major, K contiguous);
// C: fp32 [m][256][NP] or bf16.
template <int NP, bool OUTBF>
__global__ __launch_bounds__(256) void k_mixm(
    const u16* __restrict__ A, const u16* __restrict__ Bm,
    float* __restrict__ Cf, u16* __restrict__ Cb) {
  __shared__ char As[16384];
  __shared__ char Bs[16384];
  int t = threadIdx.x;
  int nt = blockIdx.x, mt = blockIdx.y, m = blockIdx.z;
  int l = t & 63, w = t >> 6;
  int wm = w >> 1, wn = w & 1;
  f32x4 acc[4][4];
#pragma unroll
  for (int a_ = 0; a_ < 4; a_++)
#pragma unroll
    for (int b_ = 0; b_ < 4; b_++) acc[a_][b_] = (f32x4){0.f, 0.f, 0.f, 0.f};
  const u16* Ab = A + ((size_t)m * 256 + mt * 128) * 256;
  const u16* Bb = Bm + ((size_t)m * NP + nt * 128) * 256;
  int srow = t >> 3, ss = t & 7;
  uint4 ra[4], rb[4];
#pragma unroll
  for (int i = 0; i < 4; i++) {
    int row = i * 32 + srow;
    ra[i] = *(const uint4*)(Ab + (size_t)row * 256 + ss * 8);
    rb[i] = *(const uint4*)(Bb + (size_t)row * 256 + ss * 8);
  }
  for (int kt = 0; kt < 4; kt++) {
    if (kt) __syncthreads();
#pragma unroll
    for (int i = 0; i < 4; i++) {
      int row = i * 32 + srow;
      int sw = ((ss ^ (row & 7)) << 4);
      *(uint4*)(As + row * 128 + sw) = ra[i];
      *(uint4*)(Bs + row * 128 + sw) = rb[i];
    }
    if (kt < 3) {
#pragma unroll
      for (int i = 0; i < 4; i++) {
        int row = i * 32 + srow;
        ra[i] = *(const uint4*)(Ab + (size_t)row * 256 + (kt + 1) * 64 + ss * 8);
        rb[i] = *(const uint4*)(Bb + (size_t)row * 256 + (kt + 1) * 64 + ss * 8);
      }
    }
    __syncthreads();
#pragma unroll
    for (int kk = 0; kk < 2; kk++) {
      short8 af[4], bg[4];
#pragma unroll
      for (int fm = 0; fm < 4; fm++) {
        int row = wm * 64 + fm * 16 + (l & 15);
        int chunk = kk * 4 + (l >> 4);
        af[fm] = *(const short8*)(As + row * 128 + ((chunk ^ (row & 7)) << 4));
      }
#pragma unroll
      for (int fn = 0; fn < 4; fn++) {
        int row = wn * 64 + fn * 16 + (l & 15);
        int chunk = kk * 4 + (l >> 4);
        bg[fn] = *(const short8*)(Bs + row * 128 + ((chunk ^ (row & 7)) << 4));
      }
#pragma unroll
      for (int fm = 0; fm < 4; fm++)
#pragma unroll
        for (int fn = 0; fn < 4; fn++)
          acc[fm][fn] = __builtin_amdgcn_mfma_f32_16x16x32_bf16(
              af[fm], bg[fn], acc[fm][fn], 0, 0, 0);
    }
  }
  int cr = (l >> 4) * 4, ccol = l & 15;
#pragma unroll
  for (int fm = 0; fm < 4; fm++) {
    int row0 = mt * 128 + wm * 64 + fm * 16 + cr;
#pragma unroll
    for (int fn = 0; fn < 4; fn++) {
      int col = nt * 128 + wn * 64 + fn * 16 + ccol;
#pragma unroll
      for (int r = 0; r < 4; r++) {
        size_t idx = ((size_t)m * 256 + row0 + r) * NP + col;
        if (OUTBF)
          Cb[idx] = f2b(acc[fm][fn][r]);
        else
          Cf[idx] = acc[fm][fn][r];
      }
    }
  }
}

// ---------------- K3: score partials over low modes ------------------------
__global__ __launch_bounds__(256) void k_scores(
    const float2* __restrict__ Xlow, const ushort2* __restrict__ QKVmb,
    float* __restrict__ Spart) {
  __shared__ float2 Xs[16][17], Qs[16][17], Ks[16][17];
  int t = threadIdx.x;
  int mc = blockIdx.x;
  int bh = blockIdx.y;
  int b = bh >> 3, h = bh & 7;
  int i = t >> 4, j = t & 15;
  int bs = b * 16 + i;
  int d = j;
  int m0 = mc * 32;
  size_t xoff = ((size_t)m0 * 256 + bs) * 128 + h * 16 + d;
  size_t qoff = ((size_t)m0 * 256 + bs) * 384 + h * 16 + d;
  float2 px = Xlow[xoff];
  ushort2 uq = QKVmb[qoff];
  ushort2 uk = QKVmb[qoff + 128];
  float acc = 0.f;
  for (int mm = 0; mm < 32; mm++) {
    int m = m0 + mm;
    Xs[i][d] = px;
    Qs[i][d] = make_float2(b2f(uq.x), b2f(uq.y));
    Ks[i][d] = make_float2(b2f(uk.x), b2f(uk.y));
    __syncthreads();
    if (mm < 31) {
      px = Xlow[xoff + (size_t)(mm + 1) * 32768];
      uq = QKVmb[qoff + (size_t)(mm + 1) * 98304];
      uk = QKVmb[qoff + (size_t)(mm + 1) * 98304 + 128];
    }
    int ky = m & 15, kx = m >> 4;
    if (ky > 0) {
#pragma unroll
      for (int dd = 0; dd < 16; dd++) {
        float2 Xi = Xs[i][dd], Qi = Qs[i][dd], Xj = Xs[j][dd], Kj = Ks[j][dd];
        float qr = Xi.x + Qi.x, qi = Xi.y + Qi.y;
        float kr = Xj.x + Kj.x, ki = Xj.y + Kj.y;
        acc += 2.f * (qr * kr + qi * ki - (Xi.x * Xj.x + Xi.y * Xj.y));
      }
    } else {
#pragma unroll
      for (int dd = 0; dd < 16; dd++) {
        float2 Xi = Xs[i][dd], Qi = Qs[i][dd], Xj = Xs[j][dd], Kj = Ks[j][dd];
        float cr = Xi.x * Kj.x + Xi.y * Kj.y + Qi.x * Xj.x + Qi.y * Xj.y;
        float qk =
            (kx == 0) ? (Qi.x * Kj.x) : 0.5f * (Qi.x * Kj.x + Qi.y * Kj.y);
        acc += cr + qk;
      }
    }
    __syncthreads();
  }
  Spart[((size_t)mc * 128 + bh) * 256 + t] = acc;
}

// ---------------- K3b: assemble scores, bias, softmax ----------------------
__global__ __launch_bounds__(256) void k_softmax(
    const float* __restrict__ Spart, const float* __restrict__ Gpart,
    const float* __restrict__ biasb, float* __restrict__ attn) {
  int t = threadIdx.x;
  int bh = blockIdx.x;
  int b = bh >> 3, h = bh & 7;
  int i = t >> 4, j = t & 15;
  float acc = 0.f;
#pragma unroll
  for (int mc = 0; mc < 8; mc++)
    acc += Spart[((size_t)mc * 128 + bh) * 256 + t];
  float G = 0.f;
#pragma unroll
  for (int dc = 0; dc < 4; dc++)
    G += Gpart[((size_t)(dc * 16 + b) * 8 + h) * 256 + t];
  float score = G * (1.f / 4096.f) + acc * (1.f / 4194304.f) +
                biasb[(((b & 3) * 8 + h) * 16 + i) * 16 + j];
  float mx = score;
#pragma unroll
  for (int o = 8; o >= 1; o >>= 1) mx = fmaxf(mx, __shfl_xor(mx, o, 16));
  float e = expf(score - mx);
  float sm = e;
#pragma unroll
  for (int o = 8; o >= 1; o >>= 1) sm += __shfl_xor(sm, o, 16);
  attn[(size_t)bh * 256 + t] = e / sm;
}

// ---------------- K4: SAf[m][bs][c] = attn @ (X + Vm~)  (bf16 out) ---------
__global__ __launch_bounds__(256) void k_sav(
    const float2* __restrict__ Xlow, const ushort2* __restrict__ QKVmb,
    const float* __restrict__ attn, ushort2* __restrict__ SAfb) {
  __shared__ float at[8][16][17];
  __shared__ float2 vt[16][130];
  int t = threadIdx.x;
  int mc = blockIdx.x;
  int b = blockIdx.y;
  {
    int h = t >> 5, ii = (t >> 1) & 15, jb = (t & 1) * 8;
#pragma unroll
    for (int k = 0; k < 8; k++)
      at[h][ii][jb + k] = attn[((size_t)(b * 8 + h) * 16 + ii) * 16 + jb + k];
  }
  __syncthreads();
  int i = t >> 4, cg = t & 15;
  for (int mm = 0; mm < 16; mm++) {
    int m = mc * 16 + mm;
    int ky = m & 15, kx = m >> 4;
    {
      int jj = t >> 4;
      size_t row = (size_t)m * 256 + b * 16 + jj;
#pragma unroll
      for (int u = 0; u < 8; u++) {
        int c = cg + u * 16;
        ushort2 uv = QKVmb[row * 384 + 256 + c];
        float2 vm = make_float2(b2f(uv.x), b2f(uv.y));
        float2 xv = Xlow[row * 128 + c];
        float2 vh;
        if (ky == 0) {
          if (kx == 0)
            vh = make_float2(xv.x + vm.x, xv.y);
          else
            vh = make_float2(xv.x + 0.5f * vm.x, xv.y + 0.5f * vm.y);
        } else
          vh = make_float2(xv.x + vm.x, xv.y + vm.y);
        vt[jj][c] = vh;
      }
    }
    __syncthreads();
    float2 o8[8];
#pragma unroll
    for (int u = 0; u < 8; u++) o8[u] = make_float2(0.f, 0.f);
#pragma unroll
    for (int jj = 0; jj < 16; jj++) {
#pragma unroll
      for (int u = 0; u < 8; u++) {
        float av = at[u][i][jj];
        float2 v = vt[jj][cg + u * 16];
        o8[u].x += av * v.x;
        o8[u].y += av * v.y;
      }
    }
    size_t orow = (size_t)m * 256 + b * 16 + i;
#pragma unroll
    for (int u = 0; u < 8; u++) {
      ushort2 ub;
      ub.x = f2b(o8[u].x);
      ub.y = f2b(o8[u].y);
      SAfb[orow * 128 + cg + u * 16] = ub;
    }
    __syncthreads();
  }
}

// ---------------- K6: inverse DFT (c2r semantics) + un-shift scatter -------
__global__ __launch_bounds__(256) void k_irfft_out(
    const float2* __restrict__ OUTm, float* __restrict__ out) {
  __shared__ float2 Fm[256][17];
  __shared__ float2 gb[17][33];
  __shared__ float2 tw[32];
  int t = threadIdx.x;
  int oc = blockIdx.x;
  int bs = blockIdx.y;
  int b = bs >> 4, s = bs & 15;
  int qx = s >> 2, qy = s & 3;
  if (t < 32) {
    float sv, cv;
    sincosf(6.283185307179586f * (float)t / 32.f, &sv, &cv);
    tw[t] = make_float2(cv, sv);
  }
  {
    const float2* src = &OUTm[((size_t)t * 256 + bs) * 128 + oc * 16];
#pragma unroll
    for (int oo = 0; oo < 16; oo++) Fm[t][oo] = src[oo];
  }
  __syncthreads();
  for (int oo = 0; oo < 16; oo++) {
    {
      int x = t >> 3, kp = t & 7;
#pragma unroll
      for (int q = 0; q < 2; q++) {
        int ky = kp * 2 + q;
        float gr = 0.f, gi = 0.f;
#pragma unroll
        for (int kx = 0; kx < 16; kx++) {
          float2 F = Fm[kx * 16 + ky][oo];
          float2 w = tw[(kx * x) & 31];
          gr += F.x * w.x - F.y * w.y;
          gi += F.x * w.y + F.y * w.x;
        }
        gb[ky][x] = make_float2(gr, gi);
      }
    }
    __syncthreads();
    {
      int x = t >> 3, yb = (t & 7) * 4;
      float vals[4];
#pragma unroll
      for (int k = 0; k < 4; k++) {
        int y = yb + k;
        float v = gb[0][x].x;
#pragma unroll
        for (int ky = 1; ky < 16; ky++) {
          float2 g = gb[ky][x];
          float2 w = tw[(ky * y) & 31];
          v += 2.f * (g.x * w.x - g.y * w.y);
        }
        vals[k] = v * (1.f / 1024.f);
      }
      int uu = x + 16;
      int u2 = uu & 31;
      int qx2 = (qx + (uu >> 5)) & 3;
      int vv = yb + 16;
      int v2 = vv & 31;
      int qy2 = (qy + (vv >> 5)) & 3;
      int s2 = qx2 * 4 + qy2;
      int o_abs = oc * 16 + oo;
      float* dst = &out[(((size_t)(b * 16 + s2) * 128 + o_abs) << 10) +
                        (u2 << 5) + v2];
      *(float4*)dst = make_float4(vals[0], vals[1], vals[2], vals[3]);
    }
    __syncthreads();
  }
}

// ---------------------------------------------------------------------------
extern "C" void kernel_launch(void* const* d_in, const int* in_sizes, int n_in,
                              void* d_out, int out_size, void* d_ws,
                              size_t ws_size, hipStream_t stream) {
  (void)in_sizes;
  (void)n_in;
  const float* seq = (const float*)d_in[0];
  const float* qwr = (const float*)d_in[1];
  const float* qwi = (const float*)d_in[2];
  const float* owr = (const float*)d_in[3];
  const float* owi = (const float*)d_in[4];
  const float* cw1 = (const float*)d_in[5];
  const float* cb1 = (const float*)d_in[6];
  const float* cw2 = (const float*)d_in[7];
  const float* amask = (const float*)d_in[8];
  float* out = (float*)d_out;
  char* ws = (char*)d_ws;

  const size_t R = 100663296;  // 96 MiB region
  // Region1: Wq_s1 (f32 [m][128][384] float2) -> after build_b(q):
  //          Xlow (67,108,864) + Xbf (33,554,432); Xbf -> Wob after mix1
  float2* Wq_s1 = (float2*)ws;
  float2* Xlow = (float2*)ws;
  u16* Xbf = (u16*)(ws + 67108864);
  ushort2* Xbf2 = (ushort2*)Xbf;
  u16* Wob = Xbf;  // alias after mix1
  // Region2: QKVmb bf16 (100,663,296) -> OUTm f32 (67,108,864) after k_sav
  ushort2* QKVmb = (ushort2*)(ws + R);
  float2* OUTm = (float2*)(ws + R);
  // Region3: Wqb bf16 (100,663,296) -> SAfb (33,554,432) after mix1
  u16* Wqb = (u16*)(ws + 2 * R);
  ushort2* SAfb = (ushort2*)(ws + 2 * R);
  // Region4: Wo_s1 f32 (33,554,432)
  float2* Wo_s1 = (float2*)(ws + 3 * R);
  char* sm = ws + 3 * R + 33554432;
  float* Gpart = (float*)sm;                    // 524,288
  float* biasb = (float*)(sm + 524288);         // 32,768
  float* attn = (float*)(sm + 557056);          // 131,072
  float* Spart = (float*)(sm + 688128);         // 1,048,576
  size_t need = 3 * R + 33554432 + 1736704;

  if (ws_size < need) {
    hipMemsetAsync(d_out, 0, (size_t)out_size * 4, stream);
    return;
  }

  dim3 blk(256);
  k_transpose_w<<<dim3(24, 16), blk, 0, stream>>>(qwr, qwi, Wq_s1, 384);
  k_build_b<384><<<dim3(6, 256), blk, 0, stream>>>(Wq_s1, Wqb);
  k_transpose_w<<<dim3(8, 16), blk, 0, stream>>>(owr, owi, Wo_s1, 128);
  k_bias<<<dim3(1), blk, 0, stream>>>(cw1, cb1, cw2, amask, biasb);
  k_fwd_dft<<<dim3(4, 256), blk, 0, stream>>>(seq, Xlow, Xbf2);
  k_gram<<<dim3(4, 128), blk, 0, stream>>>(seq, Gpart);
  k_mixm<768, true><<<dim3(6, 2, 256), blk, 0, stream>>>(
      Xbf, Wqb, (float*)nullptr, (u16*)QKVmb);
  k_scores<<<dim3(8, 128), blk, 0, stream>>>(Xlow, QKVmb, Spart);
  k_softmax<<<dim3(128), blk, 0, stream>>>(Spart, Gpart, biasb, attn);
  k_build_b<128><<<dim3(2, 256), blk, 0, stream>>>(Wo_s1, Wob);
  k_sav<<<dim3(16, 16), blk, 0, stream>>>(Xlow, QKVmb, attn, SAfb);
  k_mixm<256, false><<<dim3(2, 2, 256), blk, 0, stream>>>(
      (const u16*)SAfb, Wob, (float*)OUTm, (u16*)nullptr);
  k_irfft_out<<<dim3(8, 256), blk, 0, stream>>>(OUTm, out);
}

// Round 3
// 1001.231 us; speedup vs baseline: 1.5003x; 1.0123x over previous
//
#include <hip/hip_runtime.h>
#include <hip/hip_bf16.h>
#include <math.h>

// ---------------------------------------------------------------------------
// WinFuncSelfAttention, Fourier-domain, mode-major layouts:
//   Tbf   bf16 [bs][c][1024p]          (shift-gathered spatial tiles)
//   Wdft  bf16 [512 n=(m,q)][1024 p]   (low-mode DFT matrix; q=0 cos,q=1 -sin)
//   Xlow  fp32 float2 [m][bs][128]     (low-mode DFT, fp32 accum of dftm)
//   Xbf   bf16 [m][bs][256]            (same, interleaved re/im, MFMA A)
//   Wqb   bf16 [m][768][256]           (B' = [[Br,Bi],[-Bi,Br]], N-major)
//   QKVmb bf16 ushort2 [m][bs][384]
//   SAfb  bf16 ushort2 [m][bs][128]
//   OUTm  fp32 float2 [m][bs][128]
// All big GEMMs (dft, mix1, mix2) on v_mfma_f32_16x16x32_bf16 with
// XOR-swizzled LDS and register prefetch.
// ---------------------------------------------------------------------------

#define DEVI __device__ __forceinline__
typedef unsigned short u16;
typedef unsigned int u32;
typedef __attribute__((ext_vector_type(8))) short short8;
typedef __attribute__((ext_vector_type(4))) float f32x4;

DEVI u16 f2b(float f) {
  union { __hip_bfloat16 h; u16 u; } cv;
  cv.h = __float2bfloat16(f);
  return cv.u;
}
DEVI float b2f(u16 u) { return __uint_as_float(((u32)u) << 16); }

// ---------------- K0: bias = attn_mask + log-CPB MLP -----------------------
__global__ __launch_bounds__(256) void k_bias(
    const float* __restrict__ w1, const float* __restrict__ b1,
    const float* __restrict__ w2, const float* __restrict__ amask,
    float* __restrict__ biasb) {
  __shared__ float w1s[1024];
  __shared__ float b1s[512];
  __shared__ float w2s[4096];
  int t = threadIdx.x;
  for (int k = t; k < 1024; k += 256) w1s[k] = w1[k];
  for (int k = t; k < 512; k += 256) b1s[k] = b1[k];
  for (int k = t; k < 4096; k += 256) w2s[k] = w2[k];
  __syncthreads();
  int i = t >> 4, j = t & 15;
  float r0 = (float)((i >> 2) - (j >> 2));
  float r1 = (float)((i & 3) - (j & 3));
  const float sc = 8.0f / 3.0f;  // 8 / log2(8)
  float f0 = (r0 == 0.f) ? 0.f : copysignf(log2f(1.f + fabsf(r0)) * sc, r0);
  float f1 = (r1 == 0.f) ? 0.f : copysignf(log2f(1.f + fabsf(r1)) * sc, r1);
  float o[8];
#pragma unroll
  for (int h = 0; h < 8; h++) o[h] = 0.f;
  for (int k = 0; k < 512; k++) {
    float hd = f0 * w1s[k] + f1 * w1s[512 + k] + b1s[k];
    hd = fmaxf(hd, 0.f);
#pragma unroll
    for (int h = 0; h < 8; h++) o[h] += hd * w2s[k * 8 + h];
  }
  for (int w = 0; w < 4; w++)
#pragma unroll
    for (int h = 0; h < 8; h++) {
      int idx = ((w * 8 + h) * 16 + i) * 16 + j;
      biasb[idx] = amask[idx] + o[h];
    }
}

// ---------------- T: weight transpose wr/wi[c][o][m] -> dst[m][c][o] bf16 --
__global__ __launch_bounds__(256) void k_transpose_wb(
    const float* __restrict__ wr, const float* __restrict__ wi,
    ushort2* __restrict__ dst, int N) {
  __shared__ ushort2 ld[256][17];
  int t = threadIdx.x;
  int ob = blockIdx.x * 16;
  int cb = blockIdx.y * 8;
  for (int cc = 0; cc < 8; cc++) {
    int c = cb + cc;
    for (int oo = 0; oo < 16; oo++) {
      size_t si = ((size_t)c * N + ob + oo) * 256 + t;
      ushort2 u;
      u.x = f2b(wr[si]);
      u.y = f2b(wi[si]);
      ld[t][oo] = u;
    }
    __syncthreads();
    {
      int oo = t & 15, tq = t >> 4;
#pragma unroll
      for (int mr = 0; mr < 16; mr++) {
        int m = mr * 16 + tq;
        dst[((size_t)m * 128 + c) * N + ob + oo] = ld[m][oo];
      }
    }
    __syncthreads();
  }
}

// ---------------- B-build: Ws1[m][c][o] bf16 -> Bt[m][n=2o+p][k=2c+q] ------
template <int N>
__global__ __launch_bounds__(256) void k_build_b(
    const ushort2* __restrict__ Ws1, u16* __restrict__ Bt) {
  __shared__ ushort2 tile[128][65];
  int t = threadIdx.x;
  int ob = blockIdx.x;  // 64-o chunk
  int m = blockIdx.y;
  {
    int c4 = t >> 6, o = t & 63;
    for (int cc = 0; cc < 32; cc++) {
      int c = cc * 4 + c4;
      tile[c][o] = Ws1[((size_t)m * 128 + c) * N + ob * 64 + o];
    }
  }
  __syncthreads();
  int l = t & 63, w2 = t >> 6;
  for (int rr = 0; rr < 32; rr++) {
    int r = w2 * 32 + rr;  // local n row
    int ol = r >> 1, p = r & 1;
    size_t rowoff = ((size_t)m * (2 * N) + (size_t)ob * 128 + r) * 256;
#pragma unroll
    for (int ch = 0; ch < 2; ch++) {
      int c = ch * 64 + l;
      ushort2 wv = tile[c][ol];
      ushort2 u;
      u.x = p ? wv.y : wv.x;
      u.y = p ? wv.x : (u16)(wv.y ^ 0x8000);  // bf16 negate = sign flip
      *(ushort2*)(Bt + rowoff + 2 * c) = u;
    }
  }
}

// ---------------- W-dft build: n=(m,q) rows of cos / -sin ------------------
__global__ __launch_bounds__(256) void k_build_wdft(u16* __restrict__ Wdft) {
  int n = blockIdx.x;  // 0..511
  int m = n >> 1, q = n & 1;
  int kx = m >> 4, ky = m & 15;
  int t = threadIdx.x;
#pragma unroll
  for (int i = 0; i < 4; i++) {
    int p = i * 256 + t;
    int u = p >> 5, v = p & 31;
    int ph = (kx * u + ky * v) & 31;
    float th = 6.283185307179586f * (float)ph / 32.f;
    float sv, cv;
    sincosf(th, &sv, &cv);
    Wdft[(size_t)n * 1024 + p] = f2b(q ? -sv : cv);
  }
}

// ---------------- gather: shifted spatial tiles -> Tbf[bs][c][1024] bf16 ---
__global__ __launch_bounds__(256) void k_gather(
    const float* __restrict__ seq, u16* __restrict__ Tbf) {
  int t = threadIdx.x;
  int cq = blockIdx.x;  // 0..3
  int bs = blockIdx.y;
  int b = bs >> 4, s = bs & 15;
  int qx = s >> 2, qy = s & 3;
  int u = t >> 3, vb = (t & 7) * 4;
  int uu = u + 16;
  int u2 = uu & 31;
  int qx2 = (qx + (uu >> 5)) & 3;
  int vv = vb + 16;
  int v2 = vv & 31;
  int qy2 = (qy + (vv >> 5)) & 3;
  int s2 = qx2 * 4 + qy2;
  size_t srcbase = (((size_t)(b * 16 + s2) * 128) << 10) + u2 * 32 + v2;
  size_t dstbase = (((size_t)bs * 128) << 10) + u * 32 + vb;
  for (int cc = 0; cc < 32; cc++) {
    size_t coff = (size_t)(cq * 32 + cc) << 10;
    float4 v = *(const float4*)(seq + srcbase + coff);
    ushort4 o;
    o.x = f2b(v.x);
    o.y = f2b(v.y);
    o.z = f2b(v.z);
    o.w = f2b(v.w);
    *(ushort4*)(Tbf + dstbase + coff) = o;
  }
}

// ---------------- dftm: per-bs GEMM Wdft[512][1024] @ Tbf[bs][128][1024]^T -
__global__ __launch_bounds__(512) void k_dftm(
    const u16* __restrict__ Wdft, const u16* __restrict__ Tbf,
    float2* __restrict__ Xlow, u16* __restrict__ Xbf) {
  __shared__ char As[32768];  // 256 rows x 64k bf16, swizzled
  __shared__ char Bs[16384];  // 128 rows x 64k
  int t = threadIdx.x;
  int mt = blockIdx.x, bs = blockIdx.y;
  int l = t & 63, w = t >> 6;
  int wm = w >> 1, wn = w & 1;  // 4x2 wave grid, 64x64 out each
  f32x4 acc[4][4];
#pragma unroll
  for (int a_ = 0; a_ < 4; a_++)
#pragma unroll
    for (int b_ = 0; b_ < 4; b_++) acc[a_][b_] = (f32x4){0.f, 0.f, 0.f, 0.f};
  const u16* Ab = Wdft + (size_t)mt * 256 * 1024;
  const u16* Bb = Tbf + (size_t)bs * 128 * 1024;
  int srow = t >> 3, ss = t & 7;  // srow 0..63
  uint4 ra[4], rb[2];
#pragma unroll
  for (int i = 0; i < 4; i++)
    ra[i] = *(const uint4*)(Ab + (size_t)(i * 64 + srow) * 1024 + ss * 8);
#pragma unroll
  for (int i = 0; i < 2; i++)
    rb[i] = *(const uint4*)(Bb + (size_t)(i * 64 + srow) * 1024 + ss * 8);
  for (int kt = 0; kt < 16; kt++) {
    if (kt) __syncthreads();
#pragma unroll
    for (int i = 0; i < 4; i++) {
      int row = i * 64 + srow;
      *(uint4*)(As + row * 128 + ((ss ^ (row & 7)) << 4)) = ra[i];
    }
#pragma unroll
    for (int i = 0; i < 2; i++) {
      int row = i * 64 + srow;
      *(uint4*)(Bs + row * 128 + ((ss ^ (row & 7)) << 4)) = rb[i];
    }
    if (kt < 15) {
#pragma unroll
      for (int i = 0; i < 4; i++)
        ra[i] = *(const uint4*)(Ab + (size_t)(i * 64 + srow) * 1024 +
                                (kt + 1) * 64 + ss * 8);
#pragma unroll
      for (int i = 0; i < 2; i++)
        rb[i] = *(const uint4*)(Bb + (size_t)(i * 64 + srow) * 1024 +
                                (kt + 1) * 64 + ss * 8);
    }
    __syncthreads();
#pragma unroll
    for (int kk = 0; kk < 2; kk++) {
      short8 af[4], bg[4];
#pragma unroll
      for (int fm = 0; fm < 4; fm++) {
        int row = wm * 64 + fm * 16 + (l & 15);
        int chunk = kk * 4 + (l >> 4);
        af[fm] = *(const short8*)(As + row * 128 + ((chunk ^ (row & 7)) << 4));
      }
#pragma unroll
      for (int fn = 0; fn < 4; fn++) {
        int row = wn * 64 + fn * 16 + (l & 15);
        int chunk = kk * 4 + (l >> 4);
        bg[fn] = *(const short8*)(Bs + row * 128 + ((chunk ^ (row & 7)) << 4));
      }
#pragma unroll
      for (int fm = 0; fm < 4; fm++)
#pragma unroll
        for (int fn = 0; fn < 4; fn++)
          acc[fm][fn] = __builtin_amdgcn_mfma_f32_16x16x32_bf16(
              af[fm], bg[fn], acc[fm][fn], 0, 0, 0);
    }
  }
  int cr = (l >> 4) * 4, ccol = l & 15;
#pragma unroll
  for (int fm = 0; fm < 4; fm++) {
    int nbase = mt * 256 + wm * 64 + fm * 16 + cr;
#pragma unroll
    for (int fn = 0; fn < 4; fn++) {
      int c = wn * 64 + fn * 16 + ccol;
#pragma unroll
      for (int rp = 0; rp < 4; rp += 2) {
        int n0 = nbase + rp;  // even: q=0 (re), n0+1: q=1 (im)
        size_t row = (size_t)(n0 >> 1) * 256 + bs;
        float v0 = acc[fm][fn][rp], v1 = acc[fm][fn][rp + 1];
        Xlow[row * 128 + c] = make_float2(v0, v1);
        ushort2 ub;
        ub.x = f2b(v0);
        ub.y = f2b(v1);
        *(ushort2*)(Xbf + row * 256 + 2 * c) = ub;
      }
    }
  }
}

// ---------------- K1G: spatial Gram of shifted x ---------------------------
__global__ __launch_bounds__(256) void k_gram(
    const float* __restrict__ seq, float* __restrict__ Gpart) {
  __shared__ float xt[16][65];
  int t = threadIdx.x;
  int dc = blockIdx.x;
  int bh = blockIdx.y;
  int b = bh >> 3, h = bh & 7;
  int i = t >> 4, j = t & 15;
  float acc = 0.f;
  for (int dd = 0; dd < 4; dd++) {
    int c = h * 16 + dc * 4 + dd;
    for (int ch = 0; ch < 16; ch++) {
      {
        int s = t >> 4, pbase = (t & 15) * 4;
        int qx = s >> 2, qy = s & 3;
#pragma unroll
        for (int k = 0; k < 4; k++) {
          int px = ch * 64 + pbase + k;
          int u = px >> 5, v = px & 31;
          int uu = u + 16, vv = v + 16;
          int u2 = uu & 31, v2 = vv & 31;
          int qx2 = (qx + (uu >> 5)) & 3, qy2 = (qy + (vv >> 5)) & 3;
          xt[s][pbase + k] =
              seq[(((size_t)(b * 16 + qx2 * 4 + qy2) * 128 + c) << 10) +
                  (u2 << 5) + v2];
        }
      }
      __syncthreads();
#pragma unroll 16
      for (int p = 0; p < 64; p++) acc += xt[i][p] * xt[j][p];
      __syncthreads();
    }
  }
  Gpart[((size_t)(dc * 16 + b) * 8 + h) * 256 + t] = acc;
}

// ---------------- MFMA per-mode GEMM: C[m] = A[m] (256x256) @ B[m]^T' ------
template <int NP, bool OUTBF>
__global__ __launch_bounds__(256) void k_mixm(
    const u16* __restrict__ A, const u16* __restrict__ Bm,
    float* __restrict__ Cf, u16* __restrict__ Cb) {
  __shared__ char As[16384];
  __shared__ char Bs[16384];
  int t = threadIdx.x;
  int nt = blockIdx.x, mt = blockIdx.y, m = blockIdx.z;
  int l = t & 63, w = t >> 6;
  int wm = w >> 1, wn = w & 1;
  f32x4 acc[4][4];
#pragma unroll
  for (int a_ = 0; a_ < 4; a_++)
#pragma unroll
    for (int b_ = 0; b_ < 4; b_++) acc[a_][b_] = (f32x4){0.f, 0.f, 0.f, 0.f};
  const u16* Ab = A + ((size_t)m * 256 + mt * 128) * 256;
  const u16* Bb = Bm + ((size_t)m * NP + nt * 128) * 256;
  int srow = t >> 3, ss = t & 7;
  uint4 ra[4], rb[4];
#pragma unroll
  for (int i = 0; i < 4; i++) {
    int row = i * 32 + srow;
    ra[i] = *(const uint4*)(Ab + (size_t)row * 256 + ss * 8);
    rb[i] = *(const uint4*)(Bb + (size_t)row * 256 + ss * 8);
  }
  for (int kt = 0; kt < 4; kt++) {
    if (kt) __syncthreads();
#pragma unroll
    for (int i = 0; i < 4; i++) {
      int row = i * 32 + srow;
      int sw = ((ss ^ (row & 7)) << 4);
      *(uint4*)(As + row * 128 + sw) = ra[i];
      *(uint4*)(Bs + row * 128 + sw) = rb[i];
    }
    if (kt < 3) {
#pragma unroll
      for (int i = 0; i < 4; i++) {
        int row = i * 32 + srow;
        ra[i] = *(const uint4*)(Ab + (size_t)row * 256 + (kt + 1) * 64 + ss * 8);
        rb[i] = *(const uint4*)(Bb + (size_t)row * 256 + (kt + 1) * 64 + ss * 8);
      }
    }
    __syncthreads();
#pragma unroll
    for (int kk = 0; kk < 2; kk++) {
      short8 af[4], bg[4];
#pragma unroll
      for (int fm = 0; fm < 4; fm++) {
        int row = wm * 64 + fm * 16 + (l & 15);
        int chunk = kk * 4 + (l >> 4);
        af[fm] = *(const short8*)(As + row * 128 + ((chunk ^ (row & 7)) << 4));
      }
#pragma unroll
      for (int fn = 0; fn < 4; fn++) {
        int row = wn * 64 + fn * 16 + (l & 15);
        int chunk = kk * 4 + (l >> 4);
        bg[fn] = *(const short8*)(Bs + row * 128 + ((chunk ^ (row & 7)) << 4));
      }
#pragma unroll
      for (int fm = 0; fm < 4; fm++)
#pragma unroll
        for (int fn = 0; fn < 4; fn++)
          acc[fm][fn] = __builtin_amdgcn_mfma_f32_16x16x32_bf16(
              af[fm], bg[fn], acc[fm][fn], 0, 0, 0);
    }
  }
  int cr = (l >> 4) * 4, ccol = l & 15;
#pragma unroll
  for (int fm = 0; fm < 4; fm++) {
    int row0 = mt * 128 + wm * 64 + fm * 16 + cr;
#pragma unroll
    for (int fn = 0; fn < 4; fn++) {
      int col = nt * 128 + wn * 64 + fn * 16 + ccol;
#pragma unroll
      for (int r = 0; r < 4; r++) {
        size_t idx = ((size_t)m * 256 + row0 + r) * NP + col;
        if (OUTBF)
          Cb[idx] = f2b(acc[fm][fn][r]);
        else
          Cf[idx] = acc[fm][fn][r];
      }
    }
  }
}

// ---------------- K3: score partials over low modes ------------------------
__global__ __launch_bounds__(256) void k_scores(
    const float2* __restrict__ Xlow, const ushort2* __restrict__ QKVmb,
    float* __restrict__ Spart) {
  __shared__ float2 Xs[16][17], Qs[16][17], Ks[16][17];
  int t = threadIdx.x;
  int mc = blockIdx.x;
  int bh = blockIdx.y;
  int b = bh >> 3, h = bh & 7;
  int i = t >> 4, j = t & 15;
  int bs = b * 16 + i;
  int d = j;
  int m0 = mc * 32;
  size_t xoff = ((size_t)m0 * 256 + bs) * 128 + h * 16 + d;
  size_t qoff = ((size_t)m0 * 256 + bs) * 384 + h * 16 + d;
  float2 px = Xlow[xoff];
  ushort2 uq = QKVmb[qoff];
  ushort2 uk = QKVmb[qoff + 128];
  float acc = 0.f;
  for (int mm = 0; mm < 32; mm++) {
    int m = m0 + mm;
    Xs[i][d] = px;
    Qs[i][d] = make_float2(b2f(uq.x), b2f(uq.y));
    Ks[i][d] = make_float2(b2f(uk.x), b2f(uk.y));
    __syncthreads();
    if (mm < 31) {
      px = Xlow[xoff + (size_t)(mm + 1) * 32768];
      uq = QKVmb[qoff + (size_t)(mm + 1) * 98304];
      uk = QKVmb[qoff + (size_t)(mm + 1) * 98304 + 128];
    }
    int ky = m & 15, kx = m >> 4;
    if (ky > 0) {
#pragma unroll
      for (int dd = 0; dd < 16; dd++) {
        float2 Xi = Xs[i][dd], Qi = Qs[i][dd], Xj = Xs[j][dd], Kj = Ks[j][dd];
        float qr = Xi.x + Qi.x, qi = Xi.y + Qi.y;
        float kr = Xj.x + Kj.x, ki = Xj.y + Kj.y;
        acc += 2.f * (qr * kr + qi * ki - (Xi.x * Xj.x + Xi.y * Xj.y));
      }
    } else {
#pragma unroll
      for (int dd = 0; dd < 16; dd++) {
        float2 Xi = Xs[i][dd], Qi = Qs[i][dd], Xj = Xs[j][dd], Kj = Ks[j][dd];
        float cr = Xi.x * Kj.x + Xi.y * Kj.y + Qi.x * Xj.x + Qi.y * Xj.y;
        float qk =
            (kx == 0) ? (Qi.x * Kj.x) : 0.5f * (Qi.x * Kj.x + Qi.y * Kj.y);
        acc += cr + qk;
      }
    }
    __syncthreads();
  }
  Spart[((size_t)mc * 128 + bh) * 256 + t] = acc;
}

// ---------------- K3b: assemble scores, bias, softmax ----------------------
__global__ __launch_bounds__(256) void k_softmax(
    const float* __restrict__ Spart, const float* __restrict__ Gpart,
    const float* __restrict__ biasb, float* __restrict__ attn) {
  int t = threadIdx.x;
  int bh = blockIdx.x;
  int b = bh >> 3, h = bh & 7;
  int i = t >> 4, j = t & 15;
  float acc = 0.f;
#pragma unroll
  for (int mc = 0; mc < 8; mc++)
    acc += Spart[((size_t)mc * 128 + bh) * 256 + t];
  float G = 0.f;
#pragma unroll
  for (int dc = 0; dc < 4; dc++)
    G += Gpart[((size_t)(dc * 16 + b) * 8 + h) * 256 + t];
  float score = G * (1.f / 4096.f) + acc * (1.f / 4194304.f) +
                biasb[(((b & 3) * 8 + h) * 16 + i) * 16 + j];
  float mx = score;
#pragma unroll
  for (int o = 8; o >= 1; o >>= 1) mx = fmaxf(mx, __shfl_xor(mx, o, 16));
  float e = expf(score - mx);
  float sm = e;
#pragma unroll
  for (int o = 8; o >= 1; o >>= 1) sm += __shfl_xor(sm, o, 16);
  attn[(size_t)bh * 256 + t] = e / sm;
}

// ---------------- K4: SAf[m][bs][c] = attn @ (X + Vm~)  (bf16 out) ---------
__global__ __launch_bounds__(256) void k_sav(
    const float2* __restrict__ Xlow, const ushort2* __restrict__ QKVmb,
    const float* __restrict__ attn, ushort2* __restrict__ SAfb) {
  __shared__ float at[8][16][17];
  __shared__ float2 vt[16][130];
  int t = threadIdx.x;
  int mc = blockIdx.x;
  int b = blockIdx.y;
  {
    int h = t >> 5, ii = (t >> 1) & 15, jb = (t & 1) * 8;
#pragma unroll
    for (int k = 0; k < 8; k++)
      at[h][ii][jb + k] = attn[((size_t)(b * 8 + h) * 16 + ii) * 16 + jb + k];
  }
  __syncthreads();
  int i = t >> 4, cg = t & 15;
  for (int mm = 0; mm < 16; mm++) {
    int m = mc * 16 + mm;
    int ky = m & 15, kx = m >> 4;
    {
      int jj = t >> 4;
      size_t row = (size_t)m * 256 + b * 16 + jj;
#pragma unroll
      for (int u = 0; u < 8; u++) {
        int c = cg + u * 16;
        ushort2 uv = QKVmb[row * 384 + 256 + c];
        float2 vm = make_float2(b2f(uv.x), b2f(uv.y));
        float2 xv = Xlow[row * 128 + c];
        float2 vh;
        if (ky == 0) {
          if (kx == 0)
            vh = make_float2(xv.x + vm.x, xv.y);
          else
            vh = make_float2(xv.x + 0.5f * vm.x, xv.y + 0.5f * vm.y);
        } else
          vh = make_float2(xv.x + vm.x, xv.y + vm.y);
        vt[jj][c] = vh;
      }
    }
    __syncthreads();
    float2 o8[8];
#pragma unroll
    for (int u = 0; u < 8; u++) o8[u] = make_float2(0.f, 0.f);
#pragma unroll
    for (int jj = 0; jj < 16; jj++) {
#pragma unroll
      for (int u = 0; u < 8; u++) {
        float av = at[u][i][jj];
        float2 v = vt[jj][cg + u * 16];
        o8[u].x += av * v.x;
        o8[u].y += av * v.y;
      }
    }
    size_t orow = (size_t)m * 256 + b * 16 + i;
#pragma unroll
    for (int u = 0; u < 8; u++) {
      ushort2 ub;
      ub.x = f2b(o8[u].x);
      ub.y = f2b(o8[u].y);
      SAfb[orow * 128 + cg + u * 16] = ub;
    }
    __syncthreads();
  }
}

// ---------------- K6: inverse DFT (c2r semantics) + un-shift scatter -------
__global__ __launch_bounds__(256) void k_irfft_out(
    const float2* __restrict__ OUTm, float* __restrict__ out) {
  __shared__ float2 Fm[256][17];
  __shared__ float2 gb[17][33];
  __shared__ float2 tw[32];
  int t = threadIdx.x;
  int oc = blockIdx.x;
  int bs = blockIdx.y;
  int b = bs >> 4, s = bs & 15;
  int qx = s >> 2, qy = s & 3;
  if (t < 32) {
    float sv, cv;
    sincosf(6.283185307179586f * (float)t / 32.f, &sv, &cv);
    tw[t] = make_float2(cv, sv);
  }
  {
    const float2* src = &OUTm[((size_t)t * 256 + bs) * 128 + oc * 16];
#pragma unroll
    for (int oo = 0; oo < 16; oo++) Fm[t][oo] = src[oo];
  }
  __syncthreads();
  for (int oo = 0; oo < 16; oo++) {
    {
      int x = t >> 3, kp = t & 7;
#pragma unroll
      for (int q = 0; q < 2; q++) {
        int ky = kp * 2 + q;
        float gr = 0.f, gi = 0.f;
#pragma unroll
        for (int kx = 0; kx < 16; kx++) {
          float2 F = Fm[kx * 16 + ky][oo];
          float2 w = tw[(kx * x) & 31];
          gr += F.x * w.x - F.y * w.y;
          gi += F.x * w.y + F.y * w.x;
        }
        gb[ky][x] = make_float2(gr, gi);
      }
    }
    __syncthreads();
    {
      int x = t >> 3, yb = (t & 7) * 4;
      float vals[4];
#pragma unroll
      for (int k = 0; k < 4; k++) {
        int y = yb + k;
        float v = gb[0][x].x;
#pragma unroll
        for (int ky = 1; ky < 16; ky++) {
          float2 g = gb[ky][x];
          float2 w = tw[(ky * y) & 31];
          v += 2.f * (g.x * w.x - g.y * w.y);
        }
        vals[k] = v * (1.f / 1024.f);
      }
      int uu = x + 16;
      int u2 = uu & 31;
      int qx2 = (qx + (uu >> 5)) & 3;
      int vv = yb + 16;
      int v2 = vv & 31;
      int qy2 = (qy + (vv >> 5)) & 3;
      int s2 = qx2 * 4 + qy2;
      int o_abs = oc * 16 + oo;
      float* dst = &out[(((size_t)(b * 16 + s2) * 128 + o_abs) << 10) +
                        (u2 << 5) + v2];
      *(float4*)dst = make_float4(vals[0], vals[1], vals[2], vals[3]);
    }
    __syncthreads();
  }
}

// ---------------------------------------------------------------------------
extern "C" void kernel_launch(void* const* d_in, const int* in_sizes, int n_in,
                              void* d_out, int out_size, void* d_ws,
                              size_t ws_size, hipStream_t stream) {
  (void)in_sizes;
  (void)n_in;
  const float* seq = (const float*)d_in[0];
  const float* qwr = (const float*)d_in[1];
  const float* qwi = (const float*)d_in[2];
  const float* owr = (const float*)d_in[3];
  const float* owi = (const float*)d_in[4];
  const float* cw1 = (const float*)d_in[5];
  const float* cb1 = (const float*)d_in[6];
  const float* cw2 = (const float*)d_in[7];
  const float* amask = (const float*)d_in[8];
  float* out = (float*)d_out;
  char* ws = (char*)d_ws;

  const size_t R = 100663296;  // 96 MiB region
  // R1: Wq_s1b (bf16, 50.3MB) -> after build_b<384>: Tbf (67MB) + Xbf (33.5MB)
  //     -> Wob (33.5MB, aliases Tbf after dftm)
  ushort2* Wq_s1b = (ushort2*)ws;
  u16* Tbf = (u16*)ws;
  u16* Xbf = (u16*)(ws + 67108864);
  u16* Wob = (u16*)ws;
  // R2: QKVmb (100.6MB) -> OUTm f32 (67MB) after k_sav
  ushort2* QKVmb = (ushort2*)(ws + R);
  float2* OUTm = (float2*)(ws + R);
  // R3: Wqb (100.6MB) -> SAfb (33.5MB) after mix1
  u16* Wqb = (u16*)(ws + 2 * R);
  ushort2* SAfb = (ushort2*)(ws + 2 * R);
  // R4: Wo_s1b bf16 (16.8MB)
  ushort2* Wo_s1b = (ushort2*)(ws + 3 * R);
  // Xlow fp32 (67MB)
  float2* Xlow = (float2*)(ws + 3 * R + 16777216);
  char* sm = ws + 3 * R + 16777216 + 67108864;
  u16* Wdft = (u16*)sm;                     // 1,048,576
  float* Gpart = (float*)(sm + 1048576);    // 524,288
  float* biasb = (float*)(sm + 1572864);    // 32,768
  float* attn = (float*)(sm + 1605632);     // 131,072
  float* Spart = (float*)(sm + 1736704);    // 1,048,576
  size_t need = 3 * R + 16777216 + 67108864 + 2785280;

  if (ws_size < need) {
    hipMemsetAsync(d_out, 0, (size_t)out_size * 4, stream);
    return;
  }

  dim3 blk(256);
  k_transpose_wb<<<dim3(24, 16), blk, 0, stream>>>(qwr, qwi, Wq_s1b, 384);
  k_build_b<384><<<dim3(6, 256), blk, 0, stream>>>(Wq_s1b, Wqb);
  k_transpose_wb<<<dim3(8, 16), blk, 0, stream>>>(owr, owi, Wo_s1b, 128);
  k_bias<<<dim3(1), blk, 0, stream>>>(cw1, cb1, cw2, amask, biasb);
  k_build_wdft<<<dim3(512), blk, 0, stream>>>(Wdft);
  k_gather<<<dim3(4, 256), blk, 0, stream>>>(seq, Tbf);
  k_dftm<<<dim3(2, 256), dim3(512), 0, stream>>>(Wdft, Tbf, Xlow, Xbf);
  k_gram<<<dim3(4, 128), blk, 0, stream>>>(seq, Gpart);
  k_mixm<768, true><<<dim3(6, 2, 256), blk, 0, stream>>>(
      Xbf, Wqb, (float*)nullptr, (u16*)QKVmb);
  k_scores<<<dim3(8, 128), blk, 0, stream>>>(Xlow, QKVmb, Spart);
  k_softmax<<<dim3(128), blk, 0, stream>>>(Spart, Gpart, biasb, attn);
  k_build_b<128><<<dim3(2, 256), blk, 0, stream>>>(Wo_s1b, Wob);
  k_sav<<<dim3(16, 16), blk, 0, stream>>>(Xlow, QKVmb, attn, SAfb);
  k_mixm<256, false><<<dim3(2, 2, 256), blk, 0, stream>>>(
      (const u16*)SAfb, Wob, (float*)OUTm, (u16*)nullptr);
  k_irfft_out<<<dim3(8, 256), blk, 0, stream>>>(OUTm, out);
}

// Round 4
// 787.753 us; speedup vs baseline: 1.9068x; 1.2710x over previous
//
#include <hip/hip_runtime.h>
#include <hip/hip_bf16.h>
#include <math.h>

// ---------------------------------------------------------------------------
// WinFuncSelfAttention, Fourier-domain, mode-major layouts:
//   Tbf   bf16 [bs][c][1024p]          (shift-gathered spatial tiles)
//   Wdft  bf16 [512 n=(m,q)][1024 p]   (low-mode DFT matrix; q=0 cos,q=1 -sin)
//   Xlow  fp32 float2 [m][bs][128]     (low-mode DFT, fp32 accum of dftm)
//   Xbf   bf16 [m][bs][256]            (same, interleaved re/im, MFMA A)
//   Wqb   bf16 [m][768][256]           (B' = [[Br,Bi],[-Bi,Br]], N-major)
//   QKVmb bf16 ushort2 [m][bs][384]
//   SAfb  bf16 ushort2 [m][bs][128]
//   OUTm  fp32 float2 [m][bs][128]
// mixm: 256x256 tile, 512 thr, operand-swapped MFMA (C^T frags) for packed
// sector-aligned stores; XCD-chunked block swizzle. Gram via mfma(x,x).
// ---------------------------------------------------------------------------

#define DEVI __device__ __forceinline__
typedef unsigned short u16;
typedef unsigned int u32;
typedef __attribute__((ext_vector_type(8))) short short8;
typedef __attribute__((ext_vector_type(4))) float f32x4;

DEVI u16 f2b(float f) {
  union { __hip_bfloat16 h; u16 u; } cv;
  cv.h = __float2bfloat16(f);
  return cv.u;
}
DEVI float b2f(u16 u) { return __uint_as_float(((u32)u) << 16); }

// ---------------- K0: bias = attn_mask + log-CPB MLP -----------------------
__global__ __launch_bounds__(256) void k_bias(
    const float* __restrict__ w1, const float* __restrict__ b1,
    const float* __restrict__ w2, const float* __restrict__ amask,
    float* __restrict__ biasb) {
  __shared__ float w1s[1024];
  __shared__ float b1s[512];
  __shared__ float w2s[4096];
  int t = threadIdx.x;
  for (int k = t; k < 1024; k += 256) w1s[k] = w1[k];
  for (int k = t; k < 512; k += 256) b1s[k] = b1[k];
  for (int k = t; k < 4096; k += 256) w2s[k] = w2[k];
  __syncthreads();
  int i = t >> 4, j = t & 15;
  float r0 = (float)((i >> 2) - (j >> 2));
  float r1 = (float)((i & 3) - (j & 3));
  const float sc = 8.0f / 3.0f;  // 8 / log2(8)
  float f0 = (r0 == 0.f) ? 0.f : copysignf(log2f(1.f + fabsf(r0)) * sc, r0);
  float f1 = (r1 == 0.f) ? 0.f : copysignf(log2f(1.f + fabsf(r1)) * sc, r1);
  float o[8];
#pragma unroll
  for (int h = 0; h < 8; h++) o[h] = 0.f;
  for (int k = 0; k < 512; k++) {
    float hd = f0 * w1s[k] + f1 * w1s[512 + k] + b1s[k];
    hd = fmaxf(hd, 0.f);
#pragma unroll
    for (int h = 0; h < 8; h++) o[h] += hd * w2s[k * 8 + h];
  }
  for (int w = 0; w < 4; w++)
#pragma unroll
    for (int h = 0; h < 8; h++) {
      int idx = ((w * 8 + h) * 16 + i) * 16 + j;
      biasb[idx] = amask[idx] + o[h];
    }
}

// ---------------- T: weight transpose wr/wi[c][o][m] -> dst[m][c][o] bf16 --
__global__ __launch_bounds__(256) void k_transpose_wb(
    const float* __restrict__ wr, const float* __restrict__ wi,
    ushort2* __restrict__ dst, int N) {
  __shared__ ushort2 ld[256][17];
  int t = threadIdx.x;
  int ob = blockIdx.x * 16;
  int cb = blockIdx.y * 8;
  for (int cc = 0; cc < 8; cc++) {
    int c = cb + cc;
    for (int oo = 0; oo < 16; oo++) {
      size_t si = ((size_t)c * N + ob + oo) * 256 + t;
      ushort2 u;
      u.x = f2b(wr[si]);
      u.y = f2b(wi[si]);
      ld[t][oo] = u;
    }
    __syncthreads();
    {
      int oo = t & 15, tq = t >> 4;
#pragma unroll
      for (int mr = 0; mr < 16; mr++) {
        int m = mr * 16 + tq;
        dst[((size_t)m * 128 + c) * N + ob + oo] = ld[m][oo];
      }
    }
    __syncthreads();
  }
}

// ---------------- B-build: Ws1[m][c][o] bf16 -> Bt[m][n=2o+p][k=2c+q] ------
template <int N>
__global__ __launch_bounds__(256) void k_build_b(
    const ushort2* __restrict__ Ws1, u16* __restrict__ Bt) {
  __shared__ ushort2 tile[128][65];
  int t = threadIdx.x;
  int ob = blockIdx.x;  // 64-o chunk
  int m = blockIdx.y;
  {
    int c4 = t >> 6, o = t & 63;
    for (int cc = 0; cc < 32; cc++) {
      int c = cc * 4 + c4;
      tile[c][o] = Ws1[((size_t)m * 128 + c) * N + ob * 64 + o];
    }
  }
  __syncthreads();
  int l = t & 63, w2 = t >> 6;
  for (int rr = 0; rr < 32; rr++) {
    int r = w2 * 32 + rr;  // local n row
    int ol = r >> 1, p = r & 1;
    size_t rowoff = ((size_t)m * (2 * N) + (size_t)ob * 128 + r) * 256;
#pragma unroll
    for (int ch = 0; ch < 2; ch++) {
      int c = ch * 64 + l;
      ushort2 wv = tile[c][ol];
      ushort2 u;
      u.x = p ? wv.y : wv.x;
      u.y = p ? wv.x : (u16)(wv.y ^ 0x8000);  // bf16 negate = sign flip
      *(ushort2*)(Bt + rowoff + 2 * c) = u;
    }
  }
}

// ---------------- W-dft build: n=(m,q) rows of cos / -sin ------------------
__global__ __launch_bounds__(256) void k_build_wdft(u16* __restrict__ Wdft) {
  int n = blockIdx.x;  // 0..511
  int m = n >> 1, q = n & 1;
  int kx = m >> 4, ky = m & 15;
  int t = threadIdx.x;
#pragma unroll
  for (int i = 0; i < 4; i++) {
    int p = i * 256 + t;
    int u = p >> 5, v = p & 31;
    int ph = (kx * u + ky * v) & 31;
    float th = 6.283185307179586f * (float)ph / 32.f;
    float sv, cv;
    sincosf(th, &sv, &cv);
    Wdft[(size_t)n * 1024 + p] = f2b(q ? -sv : cv);
  }
}

// ---------------- gather: shifted spatial tiles -> Tbf[bs][c][1024] bf16 ---
__global__ __launch_bounds__(256) void k_gather(
    const float* __restrict__ seq, u16* __restrict__ Tbf) {
  int t = threadIdx.x;
  int cq = blockIdx.x;  // 0..3
  int bs = blockIdx.y;
  int b = bs >> 4, s = bs & 15;
  int qx = s >> 2, qy = s & 3;
  int u = t >> 3, vb = (t & 7) * 4;
  int uu = u + 16;
  int u2 = uu & 31;
  int qx2 = (qx + (uu >> 5)) & 3;
  int vv = vb + 16;
  int v2 = vv & 31;
  int qy2 = (qy + (vv >> 5)) & 3;
  int s2 = qx2 * 4 + qy2;
  size_t srcbase = (((size_t)(b * 16 + s2) * 128) << 10) + u2 * 32 + v2;
  size_t dstbase = (((size_t)bs * 128) << 10) + u * 32 + vb;
  for (int cc = 0; cc < 32; cc++) {
    size_t coff = (size_t)(cq * 32 + cc) << 10;
    float4 v = *(const float4*)(seq + srcbase + coff);
    ushort4 o;
    o.x = f2b(v.x);
    o.y = f2b(v.y);
    o.z = f2b(v.z);
    o.w = f2b(v.w);
    *(ushort4*)(Tbf + dstbase + coff) = o;
  }
}

// ---------------- dftm: per-bs GEMM Wdft[512][1024] @ Tbf[bs][128][1024]^T -
__global__ __launch_bounds__(512) void k_dftm(
    const u16* __restrict__ Wdft, const u16* __restrict__ Tbf,
    float2* __restrict__ Xlow, u16* __restrict__ Xbf) {
  __shared__ char As[32768];  // 256 rows x 64k bf16, swizzled
  __shared__ char Bs[16384];  // 128 rows x 64k
  int t = threadIdx.x;
  int mt = blockIdx.x, bs = blockIdx.y;
  int l = t & 63, w = t >> 6;
  int wm = w >> 1, wn = w & 1;  // 4x2 wave grid, 64x64 out each
  f32x4 acc[4][4];
#pragma unroll
  for (int a_ = 0; a_ < 4; a_++)
#pragma unroll
    for (int b_ = 0; b_ < 4; b_++) acc[a_][b_] = (f32x4){0.f, 0.f, 0.f, 0.f};
  const u16* Ab = Wdft + (size_t)mt * 256 * 1024;
  const u16* Bb = Tbf + (size_t)bs * 128 * 1024;
  int srow = t >> 3, ss = t & 7;  // srow 0..63
  uint4 ra[4], rb[2];
#pragma unroll
  for (int i = 0; i < 4; i++)
    ra[i] = *(const uint4*)(Ab + (size_t)(i * 64 + srow) * 1024 + ss * 8);
#pragma unroll
  for (int i = 0; i < 2; i++)
    rb[i] = *(const uint4*)(Bb + (size_t)(i * 64 + srow) * 1024 + ss * 8);
  for (int kt = 0; kt < 16; kt++) {
    if (kt) __syncthreads();
#pragma unroll
    for (int i = 0; i < 4; i++) {
      int row = i * 64 + srow;
      *(uint4*)(As + row * 128 + ((ss ^ (row & 7)) << 4)) = ra[i];
    }
#pragma unroll
    for (int i = 0; i < 2; i++) {
      int row = i * 64 + srow;
      *(uint4*)(Bs + row * 128 + ((ss ^ (row & 7)) << 4)) = rb[i];
    }
    if (kt < 15) {
#pragma unroll
      for (int i = 0; i < 4; i++)
        ra[i] = *(const uint4*)(Ab + (size_t)(i * 64 + srow) * 1024 +
                                (kt + 1) * 64 + ss * 8);
#pragma unroll
      for (int i = 0; i < 2; i++)
        rb[i] = *(const uint4*)(Bb + (size_t)(i * 64 + srow) * 1024 +
                                (kt + 1) * 64 + ss * 8);
    }
    __syncthreads();
#pragma unroll
    for (int kk = 0; kk < 2; kk++) {
      short8 af[4], bg[4];
#pragma unroll
      for (int fm = 0; fm < 4; fm++) {
        int row = wm * 64 + fm * 16 + (l & 15);
        int chunk = kk * 4 + (l >> 4);
        af[fm] = *(const short8*)(As + row * 128 + ((chunk ^ (row & 7)) << 4));
      }
#pragma unroll
      for (int fn = 0; fn < 4; fn++) {
        int row = wn * 64 + fn * 16 + (l & 15);
        int chunk = kk * 4 + (l >> 4);
        bg[fn] = *(const short8*)(Bs + row * 128 + ((chunk ^ (row & 7)) << 4));
      }
#pragma unroll
      for (int fm = 0; fm < 4; fm++)
#pragma unroll
        for (int fn = 0; fn < 4; fn++)
          acc[fm][fn] = __builtin_amdgcn_mfma_f32_16x16x32_bf16(
              af[fm], bg[fn], acc[fm][fn], 0, 0, 0);
    }
  }
  int cr = (l >> 4) * 4, ccol = l & 15;
#pragma unroll
  for (int fm = 0; fm < 4; fm++) {
    int nbase = mt * 256 + wm * 64 + fm * 16 + cr;
#pragma unroll
    for (int fn = 0; fn < 4; fn++) {
      int c = wn * 64 + fn * 16 + ccol;
#pragma unroll
      for (int rp = 0; rp < 4; rp += 2) {
        int n0 = nbase + rp;  // even: q=0 (re), n0+1: q=1 (im)
        size_t row = (size_t)(n0 >> 1) * 256 + bs;
        float v0 = acc[fm][fn][rp], v1 = acc[fm][fn][rp + 1];
        Xlow[row * 128 + c] = make_float2(v0, v1);
        ushort2 ub;
        ub.x = f2b(v0);
        ub.y = f2b(v1);
        *(ushort2*)(Xbf + row * 256 + 2 * c) = ub;
      }
    }
  }
}

// ---------------- Gram via MFMA: G[b,h] = X X^T over (4ch x 1024p) ---------
__global__ __launch_bounds__(64) void k_gram_mfma(
    const u16* __restrict__ Tbf, float* __restrict__ Gpart) {
  int dc = blockIdx.x;  // 0..3 channel quarter
  int bh = blockIdx.y;  // 0..127
  int b = bh >> 3, h = bh & 7;
  int l = threadIdx.x;  // 0..63
  f32x4 a0 = (f32x4){0.f, 0.f, 0.f, 0.f};
  f32x4 a1 = (f32x4){0.f, 0.f, 0.f, 0.f};
  const u16* base =
      Tbf + ((size_t)(b * 16 + (l & 15)) * 128 + h * 16 + dc * 4) * 1024;
  int ko = (l >> 4) * 8;
  for (int kk = 0; kk < 128; kk += 2) {
    short8 f0 = *(const short8*)(base + kk * 32 + ko);
    short8 f1 = *(const short8*)(base + kk * 32 + 32 + ko);
    a0 = __builtin_amdgcn_mfma_f32_16x16x32_bf16(f0, f0, a0, 0, 0, 0);
    a1 = __builtin_amdgcn_mfma_f32_16x16x32_bf16(f1, f1, a1, 0, 0, 0);
  }
  float* dst = Gpart + ((size_t)(dc * 16 + b) * 8 + h) * 256;
#pragma unroll
  for (int r = 0; r < 4; r++)
    dst[((l >> 4) * 4 + r) * 16 + (l & 15)] = a0[r] + a1[r];
}

// ---------------- MFMA per-mode GEMM: C[m] = A[m](256x256) @ B[m]' ---------
// 256(M=bs) x 256(N-tile) x K=256; 8 waves (4m x 2n), operand-swapped MFMA
// so lane holds 4 consecutive n at fixed bs -> packed ushort4/float4 stores.
template <int NP, bool OUTBF>
__global__ __launch_bounds__(512) void k_mixm(
    const u16* __restrict__ A, const u16* __restrict__ Bm,
    float* __restrict__ Cf, u16* __restrict__ Cb) {
  __shared__ char lds[65536];
  char* As = lds;          // 256 rows (bs) x 64 k bf16, swizzled
  char* Bs = lds + 32768;  // 256 rows (n)  x 64 k
  int t = threadIdx.x;
  const int gx = NP / 256;
  int orig = blockIdx.y * gx + blockIdx.x;
  const int tot = gx * 256;
  int lid = (orig & 7) * (tot >> 3) + (orig >> 3);  // XCD-chunked (tot%8==0)
  int nt = lid % gx;
  int m = lid / gx;
  int l = t & 63, w = t >> 6;
  int wm = w >> 1, wn = w & 1;  // wave tile: 64 bs x 128 n
  f32x4 acc[4][8];
#pragma unroll
  for (int a_ = 0; a_ < 4; a_++)
#pragma unroll
    for (int b_ = 0; b_ < 8; b_++) acc[a_][b_] = (f32x4){0.f, 0.f, 0.f, 0.f};
  const u16* Ab = A + (size_t)m * 256 * 256;
  const u16* Bb = Bm + ((size_t)m * NP + nt * 256) * 256;
  int srow = t >> 3, ss = t & 7;  // srow 0..63, ss = k-chunk
  uint4 ra[4], rb[4];
#pragma unroll
  for (int i = 0; i < 4; i++) {
    int row = i * 64 + srow;
    ra[i] = *(const uint4*)(Ab + (size_t)row * 256 + ss * 8);
    rb[i] = *(const uint4*)(Bb + (size_t)row * 256 + ss * 8);
  }
  for (int kt = 0; kt < 4; kt++) {
    if (kt) __syncthreads();
#pragma unroll
    for (int i = 0; i < 4; i++) {
      int row = i * 64 + srow;
      int sw = ((ss ^ (row & 7)) << 4);
      *(uint4*)(As + row * 128 + sw) = ra[i];
      *(uint4*)(Bs + row * 128 + sw) = rb[i];
    }
    if (kt < 3) {
#pragma unroll
      for (int i = 0; i < 4; i++) {
        int row = i * 64 + srow;
        ra[i] =
            *(const uint4*)(Ab + (size_t)row * 256 + (kt + 1) * 64 + ss * 8);
        rb[i] =
            *(const uint4*)(Bb + (size_t)row * 256 + (kt + 1) * 64 + ss * 8);
      }
    }
    __syncthreads();
#pragma unroll
    for (int kk = 0; kk < 2; kk++) {
      short8 af[4], bg[8];
#pragma unroll
      for (int fm = 0; fm < 4; fm++) {
        int row = wm * 64 + fm * 16 + (l & 15);
        int chunk = kk * 4 + (l >> 4);
        af[fm] = *(const short8*)(As + row * 128 + ((chunk ^ (row & 7)) << 4));
      }
#pragma unroll
      for (int fn = 0; fn < 8; fn++) {
        int row = wn * 128 + fn * 16 + (l & 15);
        int chunk = kk * 4 + (l >> 4);
        bg[fn] = *(const short8*)(Bs + row * 128 + ((chunk ^ (row & 7)) << 4));
      }
#pragma unroll
      for (int fm = 0; fm < 4; fm++)
#pragma unroll
        for (int fn = 0; fn < 8; fn++)
          acc[fm][fn] = __builtin_amdgcn_mfma_f32_16x16x32_bf16(
              bg[fn], af[fm], acc[fm][fn], 0, 0, 0);  // C^T fragments
    }
  }
  // epilogue: lane holds n0..n0+3 at fixed bs -> packed stores
#pragma unroll
  for (int fm = 0; fm < 4; fm++) {
    int bs = wm * 64 + fm * 16 + (l & 15);
    size_t rowbase = ((size_t)m * 256 + bs) * NP + nt * 256;
#pragma unroll
    for (int fn = 0; fn < 8; fn++) {
      int n0 = wn * 128 + fn * 16 + (l >> 4) * 4;
      if (OUTBF) {
        ushort4 u;
        u.x = f2b(acc[fm][fn][0]);
        u.y = f2b(acc[fm][fn][1]);
        u.z = f2b(acc[fm][fn][2]);
        u.w = f2b(acc[fm][fn][3]);
        *(ushort4*)(Cb + rowbase + n0) = u;
      } else {
        *(float4*)(Cf + rowbase + n0) = make_float4(
            acc[fm][fn][0], acc[fm][fn][1], acc[fm][fn][2], acc[fm][fn][3]);
      }
    }
  }
}

// ---------------- K3: score partials over low modes ------------------------
__global__ __launch_bounds__(256) void k_scores(
    const float2* __restrict__ Xlow, const ushort2* __restrict__ QKVmb,
    float* __restrict__ Spart) {
  __shared__ float2 Xs[16][17], Qs[16][17], Ks[16][17];
  int t = threadIdx.x;
  int mc = blockIdx.x;
  int bh = blockIdx.y;
  int b = bh >> 3, h = bh & 7;
  int i = t >> 4, j = t & 15;
  int bs = b * 16 + i;
  int d = j;
  int m0 = mc * 32;
  size_t xoff = ((size_t)m0 * 256 + bs) * 128 + h * 16 + d;
  size_t qoff = ((size_t)m0 * 256 + bs) * 384 + h * 16 + d;
  float2 px = Xlow[xoff];
  ushort2 uq = QKVmb[qoff];
  ushort2 uk = QKVmb[qoff + 128];
  float acc = 0.f;
  for (int mm = 0; mm < 32; mm++) {
    int m = m0 + mm;
    Xs[i][d] = px;
    Qs[i][d] = make_float2(b2f(uq.x), b2f(uq.y));
    Ks[i][d] = make_float2(b2f(uk.x), b2f(uk.y));
    __syncthreads();
    if (mm < 31) {
      px = Xlow[xoff + (size_t)(mm + 1) * 32768];
      uq = QKVmb[qoff + (size_t)(mm + 1) * 98304];
      uk = QKVmb[qoff + (size_t)(mm + 1) * 98304 + 128];
    }
    int ky = m & 15, kx = m >> 4;
    if (ky > 0) {
#pragma unroll
      for (int dd = 0; dd < 16; dd++) {
        float2 Xi = Xs[i][dd], Qi = Qs[i][dd], Xj = Xs[j][dd], Kj = Ks[j][dd];
        float qr = Xi.x + Qi.x, qi = Xi.y + Qi.y;
        float kr = Xj.x + Kj.x, ki = Xj.y + Kj.y;
        acc += 2.f * (qr * kr + qi * ki - (Xi.x * Xj.x + Xi.y * Xj.y));
      }
    } else {
#pragma unroll
      for (int dd = 0; dd < 16; dd++) {
        float2 Xi = Xs[i][dd], Qi = Qs[i][dd], Xj = Xs[j][dd], Kj = Ks[j][dd];
        float cr = Xi.x * Kj.x + Xi.y * Kj.y + Qi.x * Xj.x + Qi.y * Xj.y;
        float qk =
            (kx == 0) ? (Qi.x * Kj.x) : 0.5f * (Qi.x * Kj.x + Qi.y * Kj.y);
        acc += cr + qk;
      }
    }
    __syncthreads();
  }
  Spart[((size_t)mc * 128 + bh) * 256 + t] = acc;
}

// ---------------- K3b: assemble scores, bias, softmax ----------------------
__global__ __launch_bounds__(256) void k_softmax(
    const float* __restrict__ Spart, const float* __restrict__ Gpart,
    const float* __restrict__ biasb, float* __restrict__ attn) {
  int t = threadIdx.x;
  int bh = blockIdx.x;
  int b = bh >> 3, h = bh & 7;
  int i = t >> 4, j = t & 15;
  float acc = 0.f;
#pragma unroll
  for (int mc = 0; mc < 8; mc++)
    acc += Spart[((size_t)mc * 128 + bh) * 256 + t];
  float G = 0.f;
#pragma unroll
  for (int dc = 0; dc < 4; dc++)
    G += Gpart[((size_t)(dc * 16 + b) * 8 + h) * 256 + t];
  float score = G * (1.f / 4096.f) + acc * (1.f / 4194304.f) +
                biasb[(((b & 3) * 8 + h) * 16 + i) * 16 + j];
  float mx = score;
#pragma unroll
  for (int o = 8; o >= 1; o >>= 1) mx = fmaxf(mx, __shfl_xor(mx, o, 16));
  float e = expf(score - mx);
  float sm = e;
#pragma unroll
  for (int o = 8; o >= 1; o >>= 1) sm += __shfl_xor(sm, o, 16);
  attn[(size_t)bh * 256 + t] = e / sm;
}

// ---------------- K4: SAf[m][bs][c] = attn @ (X + Vm~)  (bf16 out) ---------
__global__ __launch_bounds__(256) void k_sav(
    const float2* __restrict__ Xlow, const ushort2* __restrict__ QKVmb,
    const float* __restrict__ attn, ushort2* __restrict__ SAfb) {
  __shared__ float at[8][16][17];
  __shared__ float2 vt[16][130];
  int t = threadIdx.x;
  int mc = blockIdx.x;
  int b = blockIdx.y;
  {
    int h = t >> 5, ii = (t >> 1) & 15, jb = (t & 1) * 8;
#pragma unroll
    for (int k = 0; k < 8; k++)
      at[h][ii][jb + k] = attn[((size_t)(b * 8 + h) * 16 + ii) * 16 + jb + k];
  }
  __syncthreads();
  int i = t >> 4, cg = t & 15;
  for (int mm = 0; mm < 16; mm++) {
    int m = mc * 16 + mm;
    int ky = m & 15, kx = m >> 4;
    {
      int jj = t >> 4;
      size_t row = (size_t)m * 256 + b * 16 + jj;
#pragma unroll
      for (int u = 0; u < 8; u++) {
        int c = cg + u * 16;
        ushort2 uv = QKVmb[row * 384 + 256 + c];
        float2 vm = make_float2(b2f(uv.x), b2f(uv.y));
        float2 xv = Xlow[row * 128 + c];
        float2 vh;
        if (ky == 0) {
          if (kx == 0)
            vh = make_float2(xv.x + vm.x, xv.y);
          else
            vh = make_float2(xv.x + 0.5f * vm.x, xv.y + 0.5f * vm.y);
        } else
          vh = make_float2(xv.x + vm.x, xv.y + vm.y);
        vt[jj][c] = vh;
      }
    }
    __syncthreads();
    float2 o8[8];
#pragma unroll
    for (int u = 0; u < 8; u++) o8[u] = make_float2(0.f, 0.f);
#pragma unroll
    for (int jj = 0; jj < 16; jj++) {
#pragma unroll
      for (int u = 0; u < 8; u++) {
        float av = at[u][i][jj];
        float2 v = vt[jj][cg + u * 16];
        o8[u].x += av * v.x;
        o8[u].y += av * v.y;
      }
    }
    size_t orow = (size_t)m * 256 + b * 16 + i;
#pragma unroll
    for (int u = 0; u < 8; u++) {
      ushort2 ub;
      ub.x = f2b(o8[u].x);
      ub.y = f2b(o8[u].y);
      SAfb[orow * 128 + cg + u * 16] = ub;
    }
    __syncthreads();
  }
}

// ---------------- K6: inverse DFT (c2r semantics) + un-shift scatter -------
__global__ __launch_bounds__(256) void k_irfft_out(
    const float2* __restrict__ OUTm, float* __restrict__ out) {
  __shared__ float2 Fm[256][17];
  __shared__ float2 gb[17][33];
  __shared__ float2 tw[32];
  int t = threadIdx.x;
  int oc = blockIdx.x;
  int bs = blockIdx.y;
  int b = bs >> 4, s = bs & 15;
  int qx = s >> 2, qy = s & 3;
  if (t < 32) {
    float sv, cv;
    sincosf(6.283185307179586f * (float)t / 32.f, &sv, &cv);
    tw[t] = make_float2(cv, sv);
  }
  {
    const float2* src = &OUTm[((size_t)t * 256 + bs) * 128 + oc * 16];
#pragma unroll
    for (int oo = 0; oo < 16; oo++) Fm[t][oo] = src[oo];
  }
  __syncthreads();
  for (int oo = 0; oo < 16; oo++) {
    {
      int x = t >> 3, kp = t & 7;
#pragma unroll
      for (int q = 0; q < 2; q++) {
        int ky = kp * 2 + q;
        float gr = 0.f, gi = 0.f;
#pragma unroll
        for (int kx = 0; kx < 16; kx++) {
          float2 F = Fm[kx * 16 + ky][oo];
          float2 w = tw[(kx * x) & 31];
          gr += F.x * w.x - F.y * w.y;
          gi += F.x * w.y + F.y * w.x;
        }
        gb[ky][x] = make_float2(gr, gi);
      }
    }
    __syncthreads();
    {
      int x = t >> 3, yb = (t & 7) * 4;
      float vals[4];
#pragma unroll
      for (int k = 0; k < 4; k++) {
        int y = yb + k;
        float v = gb[0][x].x;
#pragma unroll
        for (int ky = 1; ky < 16; ky++) {
          float2 g = gb[ky][x];
          float2 w = tw[(ky * y) & 31];
          v += 2.f * (g.x * w.x - g.y * w.y);
        }
        vals[k] = v * (1.f / 1024.f);
      }
      int uu = x + 16;
      int u2 = uu & 31;
      int qx2 = (qx + (uu >> 5)) & 3;
      int vv = yb + 16;
      int v2 = vv & 31;
      int qy2 = (qy + (vv >> 5)) & 3;
      int s2 = qx2 * 4 + qy2;
      int o_abs = oc * 16 + oo;
      float* dst = &out[(((size_t)(b * 16 + s2) * 128 + o_abs) << 10) +
                        (u2 << 5) + v2];
      *(float4*)dst = make_float4(vals[0], vals[1], vals[2], vals[3]);
    }
    __syncthreads();
  }
}

// ---------------------------------------------------------------------------
extern "C" void kernel_launch(void* const* d_in, const int* in_sizes, int n_in,
                              void* d_out, int out_size, void* d_ws,
                              size_t ws_size, hipStream_t stream) {
  (void)in_sizes;
  (void)n_in;
  const float* seq = (const float*)d_in[0];
  const float* qwr = (const float*)d_in[1];
  const float* qwi = (const float*)d_in[2];
  const float* owr = (const float*)d_in[3];
  const float* owi = (const float*)d_in[4];
  const float* cw1 = (const float*)d_in[5];
  const float* cb1 = (const float*)d_in[6];
  const float* cw2 = (const float*)d_in[7];
  const float* amask = (const float*)d_in[8];
  float* out = (float*)d_out;
  char* ws = (char*)d_ws;

  const size_t R = 100663296;  // 96 MiB region
  // R1: Wq_s1b (bf16, 50.3MB) -> after build_b<384>: Tbf (67MB) + Xbf (33.5MB)
  //     -> Wob (33.5MB, aliases Tbf after gram_mfma)
  ushort2* Wq_s1b = (ushort2*)ws;
  u16* Tbf = (u16*)ws;
  u16* Xbf = (u16*)(ws + 67108864);
  u16* Wob = (u16*)ws;
  // R2: QKVmb (100.6MB) -> OUTm f32 (67MB) after k_sav
  ushort2* QKVmb = (ushort2*)(ws + R);
  float2* OUTm = (float2*)(ws + R);
  // R3: Wqb (100.6MB) -> SAfb (33.5MB) after mix1
  u16* Wqb = (u16*)(ws + 2 * R);
  ushort2* SAfb = (ushort2*)(ws + 2 * R);
  // R4: Wo_s1b bf16 (16.8MB)
  ushort2* Wo_s1b = (ushort2*)(ws + 3 * R);
  // Xlow fp32 (67MB)
  float2* Xlow = (float2*)(ws + 3 * R + 16777216);
  char* sm = ws + 3 * R + 16777216 + 67108864;
  u16* Wdft = (u16*)sm;                   // 1,048,576
  float* Gpart = (float*)(sm + 1048576);  // 524,288
  float* biasb = (float*)(sm + 1572864);  // 32,768
  float* attn = (float*)(sm + 1605632);   // 131,072
  float* Spart = (float*)(sm + 1736704);  // 1,048,576
  size_t need = 3 * R + 16777216 + 67108864 + 2785280;

  if (ws_size < need) {
    hipMemsetAsync(d_out, 0, (size_t)out_size * 4, stream);
    return;
  }

  dim3 blk(256);
  k_transpose_wb<<<dim3(24, 16), blk, 0, stream>>>(qwr, qwi, Wq_s1b, 384);
  k_build_b<384><<<dim3(6, 256), blk, 0, stream>>>(Wq_s1b, Wqb);
  k_transpose_wb<<<dim3(8, 16), blk, 0, stream>>>(owr, owi, Wo_s1b, 128);
  k_bias<<<dim3(1), blk, 0, stream>>>(cw1, cb1, cw2, amask, biasb);
  k_build_wdft<<<dim3(512), blk, 0, stream>>>(Wdft);
  k_gather<<<dim3(4, 256), blk, 0, stream>>>(seq, Tbf);
  k_dftm<<<dim3(2, 256), dim3(512), 0, stream>>>(Wdft, Tbf, Xlow, Xbf);
  k_gram_mfma<<<dim3(4, 128), dim3(64), 0, stream>>>(Tbf, Gpart);
  k_mixm<768, true><<<dim3(3, 256), dim3(512), 0, stream>>>(
      Xbf, Wqb, (float*)nullptr, (u16*)QKVmb);
  k_scores<<<dim3(8, 128), blk, 0, stream>>>(Xlow, QKVmb, Spart);
  k_softmax<<<dim3(128), blk, 0, stream>>>(Spart, Gpart, biasb, attn);
  k_build_b<128><<<dim3(2, 256), blk, 0, stream>>>(Wo_s1b, Wob);
  k_sav<<<dim3(16, 16), blk, 0, stream>>>(Xlow, QKVmb, attn, SAfb);
  k_mixm<256, false><<<dim3(1, 256), dim3(512), 0, stream>>>(
      (const u16*)SAfb, Wob, (float*)OUTm, (u16*)nullptr);
  k_irfft_out<<<dim3(8, 256), blk, 0, stream>>>(OUTm, out);
}